// Round 9
// baseline (325.977 us; speedup 1.0000x reference)
//
#include <hip/hip_runtime.h>
#include <hip/hip_bf16.h>
#include <math.h>

// MultiHeadAttention  B=4, T=2048, D=512, H=8, DH=64, fp32 in/out.
// R9: grid-order swap for projections (W L2-resident, A read-once from HBM),
// projqkv reads f32 inputs directly (in-register bf16 pack, cvt kernels
// dropped), wtrans merged. Attention kernel unchanged from R8 (98us).

#define TB 2048
#define DD 512
#define NH 8
#define DH 64

typedef short bf16x8 __attribute__((ext_vector_type(8)));
typedef float f32x4 __attribute__((ext_vector_type(4)));

static __device__ __forceinline__ ushort f2bf(float x) {
  __hip_bfloat16 h = __float2bfloat16(x);
  return *reinterpret_cast<ushort*>(&h);
}
static __device__ __forceinline__ float bf2f(ushort u) {
  unsigned int v = ((unsigned int)u) << 16;
  return __uint_as_float(v);
}
static __device__ __forceinline__ float fast_exp2(float x) {
  return __builtin_amdgcn_exp2f(x);  // v_exp_f32: D = 2^S0
}
// pack2(x,y): low16 = bf16(x), high16 = bf16(y), round-half-up (R8-verified)
static __device__ __forceinline__ unsigned pack2(float x, float y) {
  return __builtin_amdgcn_perm(__float_as_uint(y) + 0x8000u,
                               __float_as_uint(x) + 0x8000u, 0x07060302u);
}
static __device__ __forceinline__ bf16x8 cvt8(float4 lo, float4 hi) {
  union { unsigned u[4]; bf16x8 v; } r;
  r.u[0] = pack2(lo.x, lo.y);
  r.u[1] = pack2(lo.z, lo.w);
  r.u[2] = pack2(hi.x, hi.y);
  r.u[3] = pack2(hi.z, hi.w);
  return r.v;
}

// ---------------------------------------------------------------------------
// Mask canonicalization (verified R1-R8). Output: float bias 0 / -inf.
__global__ void mask_detect_kernel(const unsigned char* __restrict__ m,
                                   int* __restrict__ mode) {
  __shared__ int c1, c2;
  if (threadIdx.x == 0) { c1 = 0; c2 = 0; }
  __syncthreads();
  int l1 = 0, l2 = 0;
  for (int i = threadIdx.x; i < 8192; i += blockDim.x) {
    int ph = i & 3;
    unsigned char v = m[i];
    if (ph == 1 && v) l1++;
    if (ph == 2 && v) l2++;
  }
  if (l1) atomicAdd(&c1, l1);
  if (l2) atomicAdd(&c2, l2);
  __syncthreads();
  if (threadIdx.x == 0) *mode = (c1 > 0) ? 0 : ((c2 > 0) ? 1 : 2);
}

__global__ void mask_build_kernel(const void* __restrict__ m,
                                  const int* __restrict__ mode,
                                  float* __restrict__ out) {
  int i = blockIdx.x * blockDim.x + threadIdx.x;
  int md = *mode;
  int v;
  if (md == 0)      v = ((const unsigned char*)m)[i] != 0;
  else if (md == 1) v = ((const float*)m)[i] != 0.0f;
  else              v = ((const int*)m)[i] != 0;
  out[i] = v ? 0.0f : -INFINITY;
}

// ---------------------------------------------------------------------------
// W [K][N] f32 -> Wt [N][K] bf16, 3 sections (z = Q/K/V).
__global__ __launch_bounds__(256) void wtrans3_kernel(
    const float* __restrict__ Wq, const float* __restrict__ Wk,
    const float* __restrict__ Wv, ushort* __restrict__ Wall) {
  __shared__ ushort t[64][68];
  const float* W = (blockIdx.z == 0) ? Wq : (blockIdx.z == 1) ? Wk : Wv;
  ushort* Wt = Wall + (size_t)blockIdx.z * (512 * 512);
  const int bn = blockIdx.x << 6, bk = blockIdx.y << 6;
  const int tx = threadIdx.x & 15, ty = threadIdx.x >> 4;
#pragma unroll
  for (int rr = 0; rr < 64; rr += 16) {
    float4 v = *(const float4*)&W[(size_t)(bk + rr + ty) * DD + bn + (tx << 2)];
    t[(tx << 2) + 0][rr + ty] = f2bf(v.x);
    t[(tx << 2) + 1][rr + ty] = f2bf(v.y);
    t[(tx << 2) + 2][rr + ty] = f2bf(v.z);
    t[(tx << 2) + 3][rr + ty] = f2bf(v.w);
  }
  __syncthreads();
#pragma unroll
  for (int rr = 0; rr < 64; rr += 16) {
    ushort4 o;
    o.x = t[rr + ty][(tx << 2) + 0];
    o.y = t[rr + ty][(tx << 2) + 1];
    o.z = t[rr + ty][(tx << 2) + 2];
    o.w = t[rr + ty][(tx << 2) + 3];
    *(ushort4*)&Wt[(size_t)(bn + rr + ty) * DD + bk + (tx << 2)] = o;
  }
}

// ---------------------------------------------------------------------------
// Wo [K][N] f32 -> Wt' [N][1536]: sections [Whi | Whi | Wlo] (split-bf16).
__global__ __launch_bounds__(256) void wtrans_split_kernel(
    const float* __restrict__ W, ushort* __restrict__ Wt) {
  __shared__ ushort thi[64][68];
  __shared__ ushort tlo[64][68];
  const int bn = blockIdx.x << 6, bk = blockIdx.y << 6;
  const int tx = threadIdx.x & 15, ty = threadIdx.x >> 4;
#pragma unroll
  for (int rr = 0; rr < 64; rr += 16) {
    float4 v = *(const float4*)&W[(size_t)(bk + rr + ty) * DD + bn + (tx << 2)];
    float vv[4] = {v.x, v.y, v.z, v.w};
#pragma unroll
    for (int c = 0; c < 4; ++c) {
      ushort hi = f2bf(vv[c]);
      ushort lo = f2bf(vv[c] - bf2f(hi));
      thi[(tx << 2) + c][rr + ty] = hi;
      tlo[(tx << 2) + c][rr + ty] = lo;
    }
  }
  __syncthreads();
#pragma unroll
  for (int rr = 0; rr < 64; rr += 16) {
    ushort4 h4, l4;
    h4.x = thi[rr + ty][(tx << 2) + 0];
    h4.y = thi[rr + ty][(tx << 2) + 1];
    h4.z = thi[rr + ty][(tx << 2) + 2];
    h4.w = thi[rr + ty][(tx << 2) + 3];
    l4.x = tlo[rr + ty][(tx << 2) + 0];
    l4.y = tlo[rr + ty][(tx << 2) + 1];
    l4.z = tlo[rr + ty][(tx << 2) + 2];
    l4.w = tlo[rr + ty][(tx << 2) + 3];
    size_t rowb = (size_t)(bn + rr + ty) * 1536;
    *(ushort4*)&Wt[rowb + bk + (tx << 2)] = h4;         // sec0: Whi
    *(ushort4*)&Wt[rowb + 512 + bk + (tx << 2)] = h4;   // sec1: Whi
    *(ushort4*)&Wt[rowb + 1024 + bk + (tx << 2)] = l4;  // sec2: Wlo
  }
}

// ---------------------------------------------------------------------------
// Fused QKV projection from f32 inputs -> fragment-linear bf16 outputs.
// Grid (48 ny, 256 m-blocks): ny fastest => W panels L2-resident, A read once.
// In-register f32->bf16 pack (perm+0x8000). Layouts as R8 (verified):
// Q: [bh][qt16][c][lane][8]; K: [bh][kt64][c*4+nt][lane][8];
// V: [bh][kt64][kc*4+nt][lane][8].
__global__ __launch_bounds__(64) void projqkv_kernel(
    const float* __restrict__ Qx, const float* __restrict__ Kx,
    const float* __restrict__ Vx, const ushort* __restrict__ Wall,
    const float* __restrict__ bq, const float* __restrict__ bk,
    const float* __restrict__ bv, ushort* __restrict__ Yall, float qscale) {
  const int lane = threadIdx.x, llo = lane & 15, lhi = lane >> 4;
  const int ny = blockIdx.x;        // 0..47 (fastest)
  const int m0 = blockIdx.y << 5;
  const int sec = ny >> 4;          // 0=Q, 1=K, 2=V
  const int n0 = (ny << 5) & 511;   // within-section col base

  const float* A = (sec == 0) ? Qx : (sec == 1) ? Kx : Vx;
  const float* bias = (sec == 0) ? bq : (sec == 1) ? bk : bv;
  const float scale = (sec == 0) ? qscale : 1.0f;

  const float* Ar0 = A + (size_t)(m0 + llo) * DD;
  const float* Ar1 = Ar0 + (size_t)16 * DD;
  const ushort* Br0 = Wall + (size_t)(ny * 32 + llo) * DD;
  const ushort* Br1 = Br0 + (size_t)16 * DD;

  f32x4 a00 = {0.f,0.f,0.f,0.f}, a01 = a00, a10 = a00, a11 = a00;

  const int koff = lhi * 8;
  // lookahead-2 prologue: stage A = k-step 0, stage B = k-step 1 (f32 A regs)
  float4 fa0A = *(const float4*)&Ar0[koff];
  float4 fa0Ah = *(const float4*)&Ar0[koff + 4];
  float4 fa1A = *(const float4*)&Ar1[koff];
  float4 fa1Ah = *(const float4*)&Ar1[koff + 4];
  bf16x8 wbA0 = *(const bf16x8*)&Br0[koff];
  bf16x8 wbA1 = *(const bf16x8*)&Br1[koff];
  float4 fa0B = *(const float4*)&Ar0[32 + koff];
  float4 fa0Bh = *(const float4*)&Ar0[32 + koff + 4];
  float4 fa1B = *(const float4*)&Ar1[32 + koff];
  float4 fa1Bh = *(const float4*)&Ar1[32 + koff + 4];
  bf16x8 wbB0 = *(const bf16x8*)&Br0[32 + koff];
  bf16x8 wbB1 = *(const bf16x8*)&Br1[32 + koff];

  const int nsteps = DD >> 5;  // 16
#pragma unroll 2
  for (int ks = 0; ks < nsteps; ks += 2) {
    const int k2 = ((ks + 2 < nsteps) ? (ks + 2) * 32 : 0) + koff;
    const int k3 = ((ks + 3 < nsteps) ? (ks + 3) * 32 : 32) + koff;
    bf16x8 a0 = cvt8(fa0A, fa0Ah);
    bf16x8 a1 = cvt8(fa1A, fa1Ah);
    a00 = __builtin_amdgcn_mfma_f32_16x16x32_bf16(a0, wbA0, a00, 0, 0, 0);
    a01 = __builtin_amdgcn_mfma_f32_16x16x32_bf16(a0, wbA1, a01, 0, 0, 0);
    a10 = __builtin_amdgcn_mfma_f32_16x16x32_bf16(a1, wbA0, a10, 0, 0, 0);
    a11 = __builtin_amdgcn_mfma_f32_16x16x32_bf16(a1, wbA1, a11, 0, 0, 0);
    fa0A = *(const float4*)&Ar0[k2];
    fa0Ah = *(const float4*)&Ar0[k2 + 4];
    fa1A = *(const float4*)&Ar1[k2];
    fa1Ah = *(const float4*)&Ar1[k2 + 4];
    wbA0 = *(const bf16x8*)&Br0[k2];
    wbA1 = *(const bf16x8*)&Br1[k2];
    bf16x8 b0 = cvt8(fa0B, fa0Bh);
    bf16x8 b1 = cvt8(fa1B, fa1Bh);
    a00 = __builtin_amdgcn_mfma_f32_16x16x32_bf16(b0, wbB0, a00, 0, 0, 0);
    a01 = __builtin_amdgcn_mfma_f32_16x16x32_bf16(b0, wbB1, a01, 0, 0, 0);
    a10 = __builtin_amdgcn_mfma_f32_16x16x32_bf16(b1, wbB0, a10, 0, 0, 0);
    a11 = __builtin_amdgcn_mfma_f32_16x16x32_bf16(b1, wbB1, a11, 0, 0, 0);
    fa0B = *(const float4*)&Ar0[k3];
    fa0Bh = *(const float4*)&Ar0[k3 + 4];
    fa1B = *(const float4*)&Ar1[k3];
    fa1Bh = *(const float4*)&Ar1[k3 + 4];
    wbB0 = *(const bf16x8*)&Br0[k3];
    wbB1 = *(const bf16x8*)&Br1[k3];
  }

  float bb[2];
#pragma unroll
  for (int ni = 0; ni < 2; ++ni) bb[ni] = bias[n0 + ni * 16 + llo];

  ushort* Yq = Yall;
  ushort* Yk = Yall + ((size_t)4 << 20);
  ushort* Yv = Yall + ((size_t)8 << 20);
  const f32x4 accs[2][2] = {{a00, a01}, {a10, a11}};
#pragma unroll
  for (int mi = 0; mi < 2; ++mi)
#pragma unroll
    for (int ni = 0; ni < 2; ++ni) {
      int col = n0 + ni * 16 + llo;
      int h = col >> 6, dh = col & (DH - 1);
#pragma unroll
      for (int r = 0; r < 4; ++r) {
        int row = m0 + mi * 16 + lhi * 4 + r;
        int bidx = row >> 11, t = row & (TB - 1);
        int bh = bidx * NH + h;
        ushort u = f2bf((accs[mi][ni][r] + bb[ni]) * scale);
        if (sec == 0) {
          Yq[((size_t)(bh * 128 + (t >> 4)) * 2 + (dh >> 5)) * 512 +
             ((((dh >> 3) & 3) << 4) + (t & 15)) * 8 + (dh & 7)] = u;
        } else if (sec == 1) {
          Yk[((size_t)(bh * 32 + (t >> 6)) << 12) +
             (((dh >> 5) << 2) + ((t >> 4) & 3)) * 512 +
             ((((dh >> 3) & 3) << 4) + (t & 15)) * 8 + (dh & 7)] = u;
        } else {
          Yv[((size_t)(bh * 32 + (t >> 6)) << 12) +
             ((((t >> 5) & 1) << 2) + (dh >> 4)) * 512 +
             ((((t >> 3) & 3) << 4) + (dh & 15)) * 8 + (t & 7)] = u;
        }
      }
    }
}

// ---------------------------------------------------------------------------
// O-projection: A' [8192][1536] split-bf16 @ Wot [512][1536] -> f32 + bias.
// Grid (16 n, 256 m): n fastest => Wot L2-resident, A' read once.
__global__ __launch_bounds__(64) void projo_kernel(
    const ushort* __restrict__ A, const ushort* __restrict__ Wt,
    const float* __restrict__ bias, float* __restrict__ Y) {
  const int lane = threadIdx.x, llo = lane & 15, lhi = lane >> 4;
  const int n0 = blockIdx.x << 5, m0 = blockIdx.y << 5;
  const int K = 1536;
  const ushort* Ar0 = A + (size_t)(m0 + llo) * K;
  const ushort* Ar1 = Ar0 + (size_t)16 * K;
  const ushort* Br0 = Wt + (size_t)(n0 + llo) * K;
  const ushort* Br1 = Br0 + (size_t)16 * K;

  f32x4 a00 = {0.f,0.f,0.f,0.f}, a01 = a00, a10 = a00, a11 = a00;

  const int koff = lhi * 8;
  bf16x8 aA0 = *(const bf16x8*)&Ar0[koff];
  bf16x8 aA1 = *(const bf16x8*)&Ar1[koff];
  bf16x8 bA0 = *(const bf16x8*)&Br0[koff];
  bf16x8 bA1 = *(const bf16x8*)&Br1[koff];
  bf16x8 aB0 = *(const bf16x8*)&Ar0[32 + koff];
  bf16x8 aB1 = *(const bf16x8*)&Ar1[32 + koff];
  bf16x8 bB0 = *(const bf16x8*)&Br0[32 + koff];
  bf16x8 bB1 = *(const bf16x8*)&Br1[32 + koff];

  const int nsteps = K >> 5;  // 48
  for (int ks = 0; ks < nsteps; ks += 2) {
    const int k2 = ((ks + 2 < nsteps) ? (ks + 2) * 32 : 0) + koff;
    const int k3 = ((ks + 3 < nsteps) ? (ks + 3) * 32 : 32) + koff;
    a00 = __builtin_amdgcn_mfma_f32_16x16x32_bf16(aA0, bA0, a00, 0, 0, 0);
    a01 = __builtin_amdgcn_mfma_f32_16x16x32_bf16(aA0, bA1, a01, 0, 0, 0);
    a10 = __builtin_amdgcn_mfma_f32_16x16x32_bf16(aA1, bA0, a10, 0, 0, 0);
    a11 = __builtin_amdgcn_mfma_f32_16x16x32_bf16(aA1, bA1, a11, 0, 0, 0);
    aA0 = *(const bf16x8*)&Ar0[k2];
    aA1 = *(const bf16x8*)&Ar1[k2];
    bA0 = *(const bf16x8*)&Br0[k2];
    bA1 = *(const bf16x8*)&Br1[k2];
    a00 = __builtin_amdgcn_mfma_f32_16x16x32_bf16(aB0, bB0, a00, 0, 0, 0);
    a01 = __builtin_amdgcn_mfma_f32_16x16x32_bf16(aB0, bB1, a01, 0, 0, 0);
    a10 = __builtin_amdgcn_mfma_f32_16x16x32_bf16(aB1, bB0, a10, 0, 0, 0);
    a11 = __builtin_amdgcn_mfma_f32_16x16x32_bf16(aB1, bB1, a11, 0, 0, 0);
    aB0 = *(const bf16x8*)&Ar0[k3];
    aB1 = *(const bf16x8*)&Ar1[k3];
    bB0 = *(const bf16x8*)&Br0[k3];
    bB1 = *(const bf16x8*)&Br1[k3];
  }

  float bb[2];
#pragma unroll
  for (int ni = 0; ni < 2; ++ni) bb[ni] = bias[n0 + ni * 16 + llo];
  const f32x4 accs[2][2] = {{a00, a01}, {a10, a11}};
#pragma unroll
  for (int mi = 0; mi < 2; ++mi)
#pragma unroll
    for (int ni = 0; ni < 2; ++ni)
#pragma unroll
      for (int r = 0; r < 4; ++r) {
        int row = m0 + mi * 16 + lhi * 4 + r;
        int col = n0 + ni * 16 + llo;
        Y[(size_t)row * DD + col] = accs[mi][ni][r] + bb[ni];
      }
}

// ---------------------------------------------------------------------------
// Swapped-QK^T bf16 MFMA flash attention, fragment-linear operands.
// UNCHANGED from R8 (verified: 98us, MfmaUtil 14.5%).
__global__ __launch_bounds__(256) void attn_mfma_kernel(
    const ushort* __restrict__ Qf,    // frag-linear, scaled 0.125*log2e
    const ushort* __restrict__ Kf,    // frag-linear
    const ushort* __restrict__ Vf,    // frag-linear (V^T frags)
    const float* __restrict__ mbias,  // [B][T] 0 / -inf
    ushort* __restrict__ Ap) {        // A' [8192][1536]
  __shared__ __align__(16) ushort Plds[4][16][72];

  const int tid = threadIdx.x;
  const int w = tid >> 6, lane = tid & 63;
  const int lhi = lane >> 4, llo = lane & 15;
  const int lane8 = lane * 8;

  const int bid = blockIdx.x;
  const int j = bid >> 3;
  const int bh = (bid & 7) + ((j >> 5) << 3);  // same-bh blocks -> same XCD
  const int qt = j & 31;
  const int b = bh >> 3, h = bh & 7;
  const int q0 = qt << 6;

  const float* mb = mbias + b * TB;
  ushort* pl = &Plds[w][0][0];  // [16][72]

  const ushort* Qb = Qf + ((size_t)((bh << 7) + (q0 >> 4) + w) * 2) * 512 + lane8;
  bf16x8 qa0 = *(const bf16x8*)Qb;
  bf16x8 qa1 = *(const bf16x8*)(Qb + 512);

  const size_t bhK = (size_t)bh << 5;
  f32x4 oacc[4];
#pragma unroll
  for (int nt = 0; nt < 4; ++nt) oacc[nt] = (f32x4){0.f, 0.f, 0.f, 0.f};
  float m = -INFINITY, l = 0.f;

  for (int kt64 = 0; kt64 < 32; ++kt64) {
    const ushort* Kt = Kf + ((bhK + kt64) << 12) + lane8;
    const ushort* Vt = Vf + ((bhK + kt64) << 12) + lane8;
    bf16x8 kf[8];
#pragma unroll
    for (int i = 0; i < 8; ++i) kf[i] = *(const bf16x8*)(Kt + i * 512);
    bf16x8 vf[8];
#pragma unroll
    for (int i = 0; i < 8; ++i) vf[i] = *(const bf16x8*)(Vt + i * 512);
    float4 mb4[4];
#pragma unroll
    for (int nt = 0; nt < 4; ++nt)
      mb4[nt] = *(const float4*)&mb[kt64 * 64 + nt * 16 + lhi * 4];

    f32x4 s[4];
    __builtin_amdgcn_s_setprio(1);
#pragma unroll
    for (int nt = 0; nt < 4; ++nt) {
      s[nt] = (f32x4){0.f, 0.f, 0.f, 0.f};
      s[nt] = __builtin_amdgcn_mfma_f32_16x16x32_bf16(kf[nt], qa0, s[nt], 0, 0, 0);
      s[nt] = __builtin_amdgcn_mfma_f32_16x16x32_bf16(kf[4 + nt], qa1, s[nt], 0, 0, 0);
    }
    __builtin_amdgcn_s_setprio(0);

#pragma unroll
    for (int nt = 0; nt < 4; ++nt) {
      s[nt][0] += mb4[nt].x;
      s[nt][1] += mb4[nt].y;
      s[nt][2] += mb4[nt].z;
      s[nt][3] += mb4[nt].w;
    }

    float mx[4];
#pragma unroll
    for (int nt = 0; nt < 4; ++nt)
      mx[nt] = fmaxf(fmaxf(s[nt][0], s[nt][1]), fmaxf(s[nt][2], s[nt][3]));
    float pmax = fmaxf(fmaxf(mx[0], mx[1]), fmaxf(mx[2], mx[3]));
    pmax = fmaxf(pmax, __shfl_xor(pmax, 16));
    pmax = fmaxf(pmax, __shfl_xor(pmax, 32));

    if (__any(pmax > m + 8.f)) {
      float newm = fmaxf(m, pmax);
      float alpha = fast_exp2(m - newm);
      float al[4];
#pragma unroll
      for (int r = 0; r < 4; ++r) al[r] = __shfl(alpha, lhi * 4 + r);
#pragma unroll
      for (int nt = 0; nt < 4; ++nt) {
        oacc[nt][0] *= al[0];
        oacc[nt][1] *= al[1];
        oacc[nt][2] *= al[2];
        oacc[nt][3] *= al[3];
      }
      l *= alpha;
      m = newm;
    }

#pragma unroll
    for (int nt = 0; nt < 4; ++nt)
#pragma unroll
      for (int r = 0; r < 4; ++r) s[nt][r] = fast_exp2(s[nt][r] - m);
    float sm[4];
#pragma unroll
    for (int nt = 0; nt < 4; ++nt)
      sm[nt] = (s[nt][0] + s[nt][1]) + (s[nt][2] + s[nt][3]);
    float rsum = (sm[0] + sm[1]) + (sm[2] + sm[3]);
    if (__any(m == -INFINITY)) {
      if (m == -INFINITY) {
        rsum = 0.f;
#pragma unroll
        for (int nt = 0; nt < 4; ++nt) s[nt] = (f32x4){0.f, 0.f, 0.f, 0.f};
      }
    }
    rsum += __shfl_xor(rsum, 16);
    rsum += __shfl_xor(rsum, 32);
    l += rsum;

#pragma unroll
    for (int nt = 0; nt < 4; ++nt) {
      unsigned int lo = pack2(s[nt][0], s[nt][1]);
      unsigned int hi = pack2(s[nt][2], s[nt][3]);
      *(uint2*)&pl[llo * 72 + nt * 16 + lhi * 4] = make_uint2(lo, hi);
    }

    __builtin_amdgcn_s_setprio(1);
#pragma unroll
    for (int kc = 0; kc < 2; ++kc) {
      bf16x8 pa = *(const bf16x8*)&pl[llo * 72 + kc * 32 + lhi * 8];
#pragma unroll
      for (int nt = 0; nt < 4; ++nt)
        oacc[nt] = __builtin_amdgcn_mfma_f32_16x16x32_bf16(pa, vf[kc * 4 + nt], oacc[nt], 0, 0, 0);
    }
    __builtin_amdgcn_s_setprio(0);
  }

  float linv = (l > 0.f) ? 1.f / l : 0.f;
  float il[4];
#pragma unroll
  for (int r = 0; r < 4; ++r) il[r] = __shfl(linv, lhi * 4 + r);
  const int t0 = q0 + w * 16 + lhi * 4;
#pragma unroll
  for (int r = 0; r < 4; ++r) {
    size_t rowb = (size_t)(b * TB + t0 + r) * 1536;
#pragma unroll
    for (int nt = 0; nt < 4; ++nt) {
      float o = oacc[nt][r] * il[r];
      ushort hi = f2bf(o);
      ushort lo = f2bf(o - bf2f(hi));
      int c = h * DH + nt * 16 + llo;
      Ap[rowb + c] = hi;
      Ap[rowb + 512 + c] = lo;
      Ap[rowb + 1024 + c] = hi;
    }
  }
}

// ---------------------------------------------------------------------------
extern "C" void kernel_launch(void* const* d_in, const int* in_sizes, int n_in,
                              void* d_out, int out_size, void* d_ws,
                              size_t ws_size, hipStream_t stream) {
  (void)in_sizes; (void)n_in; (void)out_size; (void)ws_size;
  const float* q = (const float*)d_in[0];
  const float* k = (const float*)d_in[1];
  const float* v = (const float*)d_in[2];
  const void* pm = d_in[3];
  const float* Wq = (const float*)d_in[4];
  const float* bq = (const float*)d_in[5];
  const float* Wk = (const float*)d_in[6];
  const float* bk = (const float*)d_in[7];
  const float* Wv = (const float*)d_in[8];
  const float* bv = (const float*)d_in[9];
  const float* Wo = (const float*)d_in[10];
  const float* bo = (const float*)d_in[11];

  char* ws = (char*)d_ws;
  const size_t MB = (size_t)1 << 20;
  // [0,24MB): A' (attention output, split-bf16 rows)
  ushort* Ap = (ushort*)(ws);
  // [24,25.5MB): Wall = [Wq^T | Wk^T | Wv^T] bf16
  ushort* Wall = (ushort*)(ws + 24 * MB);
  // [26,27.5MB): split O-weight
  ushort* Wot = (ushort*)(ws + 26 * MB);
  // [32,56MB): fragment-linear Q/K/V (8MB sections)
  ushort* Qh = (ushort*)(ws + 32 * MB);
  float* mbias = (float*)(ws + 56 * MB);
  int* mode = (int*)(ws + 56 * MB + 40960);

  mask_detect_kernel<<<1, 256, 0, stream>>>((const unsigned char*)pm, mode);
  mask_build_kernel<<<32, 256, 0, stream>>>(pm, mode, mbias);

  wtrans3_kernel<<<dim3(8, 8, 3), 256, 0, stream>>>(Wq, Wk, Wv, Wall);
  wtrans_split_kernel<<<dim3(8, 8), 256, 0, stream>>>(Wo, Wot);

  // Q scale folds 1/sqrt(64) * log2(e) for the exp2-domain softmax
  const float qscale = 0.125f * 1.4426950408889634f;
  projqkv_kernel<<<dim3(48, 256), 64, 0, stream>>>(q, k, v, Wall,
                                                   bq, bk, bv, Qh, qscale);

  attn_mfma_kernel<<<1024, 256, 0, stream>>>(
      Qh, Qh + ((size_t)4 << 20), Qh + ((size_t)8 << 20), mbias, Ap);

  projo_kernel<<<dim3(16, 256), 64, 0, stream>>>(Ap, Wot, bo, (float*)d_out);
}

// Round 10
// 325.632 us; speedup vs baseline: 1.0011x; 1.0011x over previous
//
#include <hip/hip_runtime.h>
#include <hip/hip_bf16.h>
#include <math.h>

// MultiHeadAttention  B=4, T=2048, D=512, H=8, DH=64, fp32 in/out.
// R10: XCD-aware pair swizzle for both projections (all n-panels sharing an
// A-row-group land on ONE XCD -> A fetched once; bid%8=XCD verified via attn
// kernel's L2 residency in R2). Attention byte-identical to R8/R9 (98us).

#define TB 2048
#define DD 512
#define NH 8
#define DH 64

typedef short bf16x8 __attribute__((ext_vector_type(8)));
typedef float f32x4 __attribute__((ext_vector_type(4)));

static __device__ __forceinline__ ushort f2bf(float x) {
  __hip_bfloat16 h = __float2bfloat16(x);
  return *reinterpret_cast<ushort*>(&h);
}
static __device__ __forceinline__ float bf2f(ushort u) {
  unsigned int v = ((unsigned int)u) << 16;
  return __uint_as_float(v);
}
static __device__ __forceinline__ float fast_exp2(float x) {
  return __builtin_amdgcn_exp2f(x);  // v_exp_f32: D = 2^S0
}
// pack2(x,y): low16 = bf16(x), high16 = bf16(y), round-half-up (R8-verified)
static __device__ __forceinline__ unsigned pack2(float x, float y) {
  return __builtin_amdgcn_perm(__float_as_uint(y) + 0x8000u,
                               __float_as_uint(x) + 0x8000u, 0x07060302u);
}
static __device__ __forceinline__ bf16x8 cvt8(float4 lo, float4 hi) {
  union { unsigned u[4]; bf16x8 v; } r;
  r.u[0] = pack2(lo.x, lo.y);
  r.u[1] = pack2(lo.z, lo.w);
  r.u[2] = pack2(hi.x, hi.y);
  r.u[3] = pack2(hi.z, hi.w);
  return r.v;
}

// ---------------------------------------------------------------------------
// Mask canonicalization (verified R1-R9). Output: float bias 0 / -inf.
__global__ void mask_detect_kernel(const unsigned char* __restrict__ m,
                                   int* __restrict__ mode) {
  __shared__ int c1, c2;
  if (threadIdx.x == 0) { c1 = 0; c2 = 0; }
  __syncthreads();
  int l1 = 0, l2 = 0;
  for (int i = threadIdx.x; i < 8192; i += blockDim.x) {
    int ph = i & 3;
    unsigned char v = m[i];
    if (ph == 1 && v) l1++;
    if (ph == 2 && v) l2++;
  }
  if (l1) atomicAdd(&c1, l1);
  if (l2) atomicAdd(&c2, l2);
  __syncthreads();
  if (threadIdx.x == 0) *mode = (c1 > 0) ? 0 : ((c2 > 0) ? 1 : 2);
}

__global__ void mask_build_kernel(const void* __restrict__ m,
                                  const int* __restrict__ mode,
                                  float* __restrict__ out) {
  int i = blockIdx.x * blockDim.x + threadIdx.x;
  int md = *mode;
  int v;
  if (md == 0)      v = ((const unsigned char*)m)[i] != 0;
  else if (md == 1) v = ((const float*)m)[i] != 0.0f;
  else              v = ((const int*)m)[i] != 0;
  out[i] = v ? 0.0f : -INFINITY;
}

// ---------------------------------------------------------------------------
// W [K][N] f32 -> Wt [N][K] bf16, 3 sections (z = Q/K/V).
__global__ __launch_bounds__(256) void wtrans3_kernel(
    const float* __restrict__ Wq, const float* __restrict__ Wk,
    const float* __restrict__ Wv, ushort* __restrict__ Wall) {
  __shared__ ushort t[64][68];
  const float* W = (blockIdx.z == 0) ? Wq : (blockIdx.z == 1) ? Wk : Wv;
  ushort* Wt = Wall + (size_t)blockIdx.z * (512 * 512);
  const int bn = blockIdx.x << 6, bk = blockIdx.y << 6;
  const int tx = threadIdx.x & 15, ty = threadIdx.x >> 4;
#pragma unroll
  for (int rr = 0; rr < 64; rr += 16) {
    float4 v = *(const float4*)&W[(size_t)(bk + rr + ty) * DD + bn + (tx << 2)];
    t[(tx << 2) + 0][rr + ty] = f2bf(v.x);
    t[(tx << 2) + 1][rr + ty] = f2bf(v.y);
    t[(tx << 2) + 2][rr + ty] = f2bf(v.z);
    t[(tx << 2) + 3][rr + ty] = f2bf(v.w);
  }
  __syncthreads();
#pragma unroll
  for (int rr = 0; rr < 64; rr += 16) {
    ushort4 o;
    o.x = t[rr + ty][(tx << 2) + 0];
    o.y = t[rr + ty][(tx << 2) + 1];
    o.z = t[rr + ty][(tx << 2) + 2];
    o.w = t[rr + ty][(tx << 2) + 3];
    *(ushort4*)&Wt[(size_t)(bn + rr + ty) * DD + bk + (tx << 2)] = o;
  }
}

// ---------------------------------------------------------------------------
// Wo [K][N] f32 -> Wt' [N][1536]: sections [Whi | Whi | Wlo] (split-bf16).
__global__ __launch_bounds__(256) void wtrans_split_kernel(
    const float* __restrict__ W, ushort* __restrict__ Wt) {
  __shared__ ushort thi[64][68];
  __shared__ ushort tlo[64][68];
  const int bn = blockIdx.x << 6, bk = blockIdx.y << 6;
  const int tx = threadIdx.x & 15, ty = threadIdx.x >> 4;
#pragma unroll
  for (int rr = 0; rr < 64; rr += 16) {
    float4 v = *(const float4*)&W[(size_t)(bk + rr + ty) * DD + bn + (tx << 2)];
    float vv[4] = {v.x, v.y, v.z, v.w};
#pragma unroll
    for (int c = 0; c < 4; ++c) {
      ushort hi = f2bf(vv[c]);
      ushort lo = f2bf(vv[c] - bf2f(hi));
      thi[(tx << 2) + c][rr + ty] = hi;
      tlo[(tx << 2) + c][rr + ty] = lo;
    }
  }
  __syncthreads();
#pragma unroll
  for (int rr = 0; rr < 64; rr += 16) {
    ushort4 h4, l4;
    h4.x = thi[rr + ty][(tx << 2) + 0];
    h4.y = thi[rr + ty][(tx << 2) + 1];
    h4.z = thi[rr + ty][(tx << 2) + 2];
    h4.w = thi[rr + ty][(tx << 2) + 3];
    l4.x = tlo[rr + ty][(tx << 2) + 0];
    l4.y = tlo[rr + ty][(tx << 2) + 1];
    l4.z = tlo[rr + ty][(tx << 2) + 2];
    l4.w = tlo[rr + ty][(tx << 2) + 3];
    size_t rowb = (size_t)(bn + rr + ty) * 1536;
    *(ushort4*)&Wt[rowb + bk + (tx << 2)] = h4;         // sec0: Whi
    *(ushort4*)&Wt[rowb + 512 + bk + (tx << 2)] = h4;   // sec1: Whi
    *(ushort4*)&Wt[rowb + 1024 + bk + (tx << 2)] = l4;  // sec2: Wlo
  }
}

// ---------------------------------------------------------------------------
// Fused QKV projection from f32 inputs -> fragment-linear bf16 outputs.
// 12288 one-wave blocks, XCD pair swizzle: all 16 n-panels of one
// (m-block, sec) pair share bid%8 -> same XCD L2 -> A rows fetched once.
__global__ __launch_bounds__(64) void projqkv_kernel(
    const float* __restrict__ Qx, const float* __restrict__ Kx,
    const float* __restrict__ Vx, const ushort* __restrict__ Wall,
    const float* __restrict__ bq, const float* __restrict__ bk,
    const float* __restrict__ bv, ushort* __restrict__ Yall, float qscale) {
  const int lane = threadIdx.x, llo = lane & 15, lhi = lane >> 4;
  const int bid = blockIdx.x;
  const int x = bid & 7;            // XCD (bid%8 round-robin)
  const int i = bid >> 3;           // per-XCD slot
  const int ny16 = i & 15;          // n-panel within section
  const int p = (i >> 4) * 8 + x;   // pair id 0..767, constant XCD per pair
  const int sec = p % 3;            // 0=Q, 1=K, 2=V
  const int mblk = p / 3;           // 0..255
  const int m0 = mblk << 5;
  const int n0 = ny16 << 5;         // within-section col base
  const int ny = sec * 16 + ny16;   // W row-panel index

  const float* A = (sec == 0) ? Qx : (sec == 1) ? Kx : Vx;
  const float* bias = (sec == 0) ? bq : (sec == 1) ? bk : bv;
  const float scale = (sec == 0) ? qscale : 1.0f;

  const float* Ar0 = A + (size_t)(m0 + llo) * DD;
  const float* Ar1 = Ar0 + (size_t)16 * DD;
  const ushort* Br0 = Wall + (size_t)(ny * 32 + llo) * DD;
  const ushort* Br1 = Br0 + (size_t)16 * DD;

  f32x4 a00 = {0.f,0.f,0.f,0.f}, a01 = a00, a10 = a00, a11 = a00;

  const int koff = lhi * 8;
  // lookahead-2 prologue: stage A = k-step 0, stage B = k-step 1 (f32 A regs)
  float4 fa0A = *(const float4*)&Ar0[koff];
  float4 fa0Ah = *(const float4*)&Ar0[koff + 4];
  float4 fa1A = *(const float4*)&Ar1[koff];
  float4 fa1Ah = *(const float4*)&Ar1[koff + 4];
  bf16x8 wbA0 = *(const bf16x8*)&Br0[koff];
  bf16x8 wbA1 = *(const bf16x8*)&Br1[koff];
  float4 fa0B = *(const float4*)&Ar0[32 + koff];
  float4 fa0Bh = *(const float4*)&Ar0[32 + koff + 4];
  float4 fa1B = *(const float4*)&Ar1[32 + koff];
  float4 fa1Bh = *(const float4*)&Ar1[32 + koff + 4];
  bf16x8 wbB0 = *(const bf16x8*)&Br0[32 + koff];
  bf16x8 wbB1 = *(const bf16x8*)&Br1[32 + koff];

  const int nsteps = DD >> 5;  // 16
#pragma unroll 2
  for (int ks = 0; ks < nsteps; ks += 2) {
    const int k2 = ((ks + 2 < nsteps) ? (ks + 2) * 32 : 0) + koff;
    const int k3 = ((ks + 3 < nsteps) ? (ks + 3) * 32 : 32) + koff;
    bf16x8 a0 = cvt8(fa0A, fa0Ah);
    bf16x8 a1 = cvt8(fa1A, fa1Ah);
    a00 = __builtin_amdgcn_mfma_f32_16x16x32_bf16(a0, wbA0, a00, 0, 0, 0);
    a01 = __builtin_amdgcn_mfma_f32_16x16x32_bf16(a0, wbA1, a01, 0, 0, 0);
    a10 = __builtin_amdgcn_mfma_f32_16x16x32_bf16(a1, wbA0, a10, 0, 0, 0);
    a11 = __builtin_amdgcn_mfma_f32_16x16x32_bf16(a1, wbA1, a11, 0, 0, 0);
    fa0A = *(const float4*)&Ar0[k2];
    fa0Ah = *(const float4*)&Ar0[k2 + 4];
    fa1A = *(const float4*)&Ar1[k2];
    fa1Ah = *(const float4*)&Ar1[k2 + 4];
    wbA0 = *(const bf16x8*)&Br0[k2];
    wbA1 = *(const bf16x8*)&Br1[k2];
    bf16x8 b0 = cvt8(fa0B, fa0Bh);
    bf16x8 b1 = cvt8(fa1B, fa1Bh);
    a00 = __builtin_amdgcn_mfma_f32_16x16x32_bf16(b0, wbB0, a00, 0, 0, 0);
    a01 = __builtin_amdgcn_mfma_f32_16x16x32_bf16(b0, wbB1, a01, 0, 0, 0);
    a10 = __builtin_amdgcn_mfma_f32_16x16x32_bf16(b1, wbB0, a10, 0, 0, 0);
    a11 = __builtin_amdgcn_mfma_f32_16x16x32_bf16(b1, wbB1, a11, 0, 0, 0);
    fa0B = *(const float4*)&Ar0[k3];
    fa0Bh = *(const float4*)&Ar0[k3 + 4];
    fa1B = *(const float4*)&Ar1[k3];
    fa1Bh = *(const float4*)&Ar1[k3 + 4];
    wbB0 = *(const bf16x8*)&Br0[k3];
    wbB1 = *(const bf16x8*)&Br1[k3];
  }

  float bb[2];
#pragma unroll
  for (int ni = 0; ni < 2; ++ni) bb[ni] = bias[n0 + ni * 16 + llo];

  ushort* Yq = Yall;
  ushort* Yk = Yall + ((size_t)4 << 20);
  ushort* Yv = Yall + ((size_t)8 << 20);
  const f32x4 accs[2][2] = {{a00, a01}, {a10, a11}};
#pragma unroll
  for (int mi = 0; mi < 2; ++mi)
#pragma unroll
    for (int ni = 0; ni < 2; ++ni) {
      int col = n0 + ni * 16 + llo;
      int h = col >> 6, dh = col & (DH - 1);
#pragma unroll
      for (int r = 0; r < 4; ++r) {
        int row = m0 + mi * 16 + lhi * 4 + r;
        int bidx = row >> 11, t = row & (TB - 1);
        int bh = bidx * NH + h;
        ushort u = f2bf((accs[mi][ni][r] + bb[ni]) * scale);
        if (sec == 0) {
          Yq[((size_t)(bh * 128 + (t >> 4)) * 2 + (dh >> 5)) * 512 +
             ((((dh >> 3) & 3) << 4) + (t & 15)) * 8 + (dh & 7)] = u;
        } else if (sec == 1) {
          Yk[((size_t)(bh * 32 + (t >> 6)) << 12) +
             (((dh >> 5) << 2) + ((t >> 4) & 3)) * 512 +
             ((((dh >> 3) & 3) << 4) + (t & 15)) * 8 + (dh & 7)] = u;
        } else {
          Yv[((size_t)(bh * 32 + (t >> 6)) << 12) +
             ((((t >> 5) & 1) << 2) + (dh >> 4)) * 512 +
             ((((t >> 3) & 3) << 4) + (dh & 15)) * 8 + (t & 7)] = u;
        }
      }
    }
}

// ---------------------------------------------------------------------------
// O-projection: A' [8192][1536] split-bf16 @ Wot [512][1536] -> f32 + bias.
// 4096 one-wave blocks, XCD swizzle: all 16 n-panels of one m-block share
// bid%8 -> A' rows fetched once per XCD.
__global__ __launch_bounds__(64) void projo_kernel(
    const ushort* __restrict__ A, const ushort* __restrict__ Wt,
    const float* __restrict__ bias, float* __restrict__ Y) {
  const int lane = threadIdx.x, llo = lane & 15, lhi = lane >> 4;
  const int bid = blockIdx.x;
  const int x = bid & 7;
  const int i = bid >> 3;
  const int n16 = i & 15;
  const int m0 = (((i >> 4) << 3) + x) << 5;  // m-block 0..255, XCD-pinned
  const int n0 = n16 << 5;
  const int K = 1536;
  const ushort* Ar0 = A + (size_t)(m0 + llo) * K;
  const ushort* Ar1 = Ar0 + (size_t)16 * K;
  const ushort* Br0 = Wt + (size_t)(n0 + llo) * K;
  const ushort* Br1 = Br0 + (size_t)16 * K;

  f32x4 a00 = {0.f,0.f,0.f,0.f}, a01 = a00, a10 = a00, a11 = a00;

  const int koff = lhi * 8;
  bf16x8 aA0 = *(const bf16x8*)&Ar0[koff];
  bf16x8 aA1 = *(const bf16x8*)&Ar1[koff];
  bf16x8 bA0 = *(const bf16x8*)&Br0[koff];
  bf16x8 bA1 = *(const bf16x8*)&Br1[koff];
  bf16x8 aB0 = *(const bf16x8*)&Ar0[32 + koff];
  bf16x8 aB1 = *(const bf16x8*)&Ar1[32 + koff];
  bf16x8 bB0 = *(const bf16x8*)&Br0[32 + koff];
  bf16x8 bB1 = *(const bf16x8*)&Br1[32 + koff];

  const int nsteps = K >> 5;  // 48
  for (int ks = 0; ks < nsteps; ks += 2) {
    const int k2 = ((ks + 2 < nsteps) ? (ks + 2) * 32 : 0) + koff;
    const int k3 = ((ks + 3 < nsteps) ? (ks + 3) * 32 : 32) + koff;
    a00 = __builtin_amdgcn_mfma_f32_16x16x32_bf16(aA0, bA0, a00, 0, 0, 0);
    a01 = __builtin_amdgcn_mfma_f32_16x16x32_bf16(aA0, bA1, a01, 0, 0, 0);
    a10 = __builtin_amdgcn_mfma_f32_16x16x32_bf16(aA1, bA0, a10, 0, 0, 0);
    a11 = __builtin_amdgcn_mfma_f32_16x16x32_bf16(aA1, bA1, a11, 0, 0, 0);
    aA0 = *(const bf16x8*)&Ar0[k2];
    aA1 = *(const bf16x8*)&Ar1[k2];
    bA0 = *(const bf16x8*)&Br0[k2];
    bA1 = *(const bf16x8*)&Br1[k2];
    a00 = __builtin_amdgcn_mfma_f32_16x16x32_bf16(aB0, bB0, a00, 0, 0, 0);
    a01 = __builtin_amdgcn_mfma_f32_16x16x32_bf16(aB0, bB1, a01, 0, 0, 0);
    a10 = __builtin_amdgcn_mfma_f32_16x16x32_bf16(aB1, bB0, a10, 0, 0, 0);
    a11 = __builtin_amdgcn_mfma_f32_16x16x32_bf16(aB1, bB1, a11, 0, 0, 0);
    aB0 = *(const bf16x8*)&Ar0[k3];
    aB1 = *(const bf16x8*)&Ar1[k3];
    bB0 = *(const bf16x8*)&Br0[k3];
    bB1 = *(const bf16x8*)&Br1[k3];
  }

  float bb[2];
#pragma unroll
  for (int ni = 0; ni < 2; ++ni) bb[ni] = bias[n0 + ni * 16 + llo];
  const f32x4 accs[2][2] = {{a00, a01}, {a10, a11}};
#pragma unroll
  for (int mi = 0; mi < 2; ++mi)
#pragma unroll
    for (int ni = 0; ni < 2; ++ni)
#pragma unroll
      for (int r = 0; r < 4; ++r) {
        int row = m0 + mi * 16 + lhi * 4 + r;
        int col = n0 + ni * 16 + llo;
        Y[(size_t)row * DD + col] = accs[mi][ni][r] + bb[ni];
      }
}

// ---------------------------------------------------------------------------
// Swapped-QK^T bf16 MFMA flash attention, fragment-linear operands.
// UNCHANGED from R8/R9 (verified: 98us, MfmaUtil 14.5%).
__global__ __launch_bounds__(256) void attn_mfma_kernel(
    const ushort* __restrict__ Qf,    // frag-linear, scaled 0.125*log2e
    const ushort* __restrict__ Kf,    // frag-linear
    const ushort* __restrict__ Vf,    // frag-linear (V^T frags)
    const float* __restrict__ mbias,  // [B][T] 0 / -inf
    ushort* __restrict__ Ap) {        // A' [8192][1536]
  __shared__ __align__(16) ushort Plds[4][16][72];

  const int tid = threadIdx.x;
  const int w = tid >> 6, lane = tid & 63;
  const int lhi = lane >> 4, llo = lane & 15;
  const int lane8 = lane * 8;

  const int bid = blockIdx.x;
  const int j = bid >> 3;
  const int bh = (bid & 7) + ((j >> 5) << 3);  // same-bh blocks -> same XCD
  const int qt = j & 31;
  const int b = bh >> 3, h = bh & 7;
  const int q0 = qt << 6;

  const float* mb = mbias + b * TB;
  ushort* pl = &Plds[w][0][0];  // [16][72]

  const ushort* Qb = Qf + ((size_t)((bh << 7) + (q0 >> 4) + w) * 2) * 512 + lane8;
  bf16x8 qa0 = *(const bf16x8*)Qb;
  bf16x8 qa1 = *(const bf16x8*)(Qb + 512);

  const size_t bhK = (size_t)bh << 5;
  f32x4 oacc[4];
#pragma unroll
  for (int nt = 0; nt < 4; ++nt) oacc[nt] = (f32x4){0.f, 0.f, 0.f, 0.f};
  float m = -INFINITY, l = 0.f;

  for (int kt64 = 0; kt64 < 32; ++kt64) {
    const ushort* Kt = Kf + ((bhK + kt64) << 12) + lane8;
    const ushort* Vt = Vf + ((bhK + kt64) << 12) + lane8;
    bf16x8 kf[8];
#pragma unroll
    for (int i = 0; i < 8; ++i) kf[i] = *(const bf16x8*)(Kt + i * 512);
    bf16x8 vf[8];
#pragma unroll
    for (int i = 0; i < 8; ++i) vf[i] = *(const bf16x8*)(Vt + i * 512);
    float4 mb4[4];
#pragma unroll
    for (int nt = 0; nt < 4; ++nt)
      mb4[nt] = *(const float4*)&mb[kt64 * 64 + nt * 16 + lhi * 4];

    f32x4 s[4];
    __builtin_amdgcn_s_setprio(1);
#pragma unroll
    for (int nt = 0; nt < 4; ++nt) {
      s[nt] = (f32x4){0.f, 0.f, 0.f, 0.f};
      s[nt] = __builtin_amdgcn_mfma_f32_16x16x32_bf16(kf[nt], qa0, s[nt], 0, 0, 0);
      s[nt] = __builtin_amdgcn_mfma_f32_16x16x32_bf16(kf[4 + nt], qa1, s[nt], 0, 0, 0);
    }
    __builtin_amdgcn_s_setprio(0);

#pragma unroll
    for (int nt = 0; nt < 4; ++nt) {
      s[nt][0] += mb4[nt].x;
      s[nt][1] += mb4[nt].y;
      s[nt][2] += mb4[nt].z;
      s[nt][3] += mb4[nt].w;
    }

    float mx[4];
#pragma unroll
    for (int nt = 0; nt < 4; ++nt)
      mx[nt] = fmaxf(fmaxf(s[nt][0], s[nt][1]), fmaxf(s[nt][2], s[nt][3]));
    float pmax = fmaxf(fmaxf(mx[0], mx[1]), fmaxf(mx[2], mx[3]));
    pmax = fmaxf(pmax, __shfl_xor(pmax, 16));
    pmax = fmaxf(pmax, __shfl_xor(pmax, 32));

    if (__any(pmax > m + 8.f)) {
      float newm = fmaxf(m, pmax);
      float alpha = fast_exp2(m - newm);
      float al[4];
#pragma unroll
      for (int r = 0; r < 4; ++r) al[r] = __shfl(alpha, lhi * 4 + r);
#pragma unroll
      for (int nt = 0; nt < 4; ++nt) {
        oacc[nt][0] *= al[0];
        oacc[nt][1] *= al[1];
        oacc[nt][2] *= al[2];
        oacc[nt][3] *= al[3];
      }
      l *= alpha;
      m = newm;
    }

#pragma unroll
    for (int nt = 0; nt < 4; ++nt)
#pragma unroll
      for (int r = 0; r < 4; ++r) s[nt][r] = fast_exp2(s[nt][r] - m);
    float sm[4];
#pragma unroll
    for (int nt = 0; nt < 4; ++nt)
      sm[nt] = (s[nt][0] + s[nt][1]) + (s[nt][2] + s[nt][3]);
    float rsum = (sm[0] + sm[1]) + (sm[2] + sm[3]);
    if (__any(m == -INFINITY)) {
      if (m == -INFINITY) {
        rsum = 0.f;
#pragma unroll
        for (int nt = 0; nt < 4; ++nt) s[nt] = (f32x4){0.f, 0.f, 0.f, 0.f};
      }
    }
    rsum += __shfl_xor(rsum, 16);
    rsum += __shfl_xor(rsum, 32);
    l += rsum;

#pragma unroll
    for (int nt = 0; nt < 4; ++nt) {
      unsigned int lo = pack2(s[nt][0], s[nt][1]);
      unsigned int hi = pack2(s[nt][2], s[nt][3]);
      *(uint2*)&pl[llo * 72 + nt * 16 + lhi * 4] = make_uint2(lo, hi);
    }

    __builtin_amdgcn_s_setprio(1);
#pragma unroll
    for (int kc = 0; kc < 2; ++kc) {
      bf16x8 pa = *(const bf16x8*)&pl[llo * 72 + kc * 32 + lhi * 8];
#pragma unroll
      for (int nt = 0; nt < 4; ++nt)
        oacc[nt] = __builtin_amdgcn_mfma_f32_16x16x32_bf16(pa, vf[kc * 4 + nt], oacc[nt], 0, 0, 0);
    }
    __builtin_amdgcn_s_setprio(0);
  }

  float linv = (l > 0.f) ? 1.f / l : 0.f;
  float il[4];
#pragma unroll
  for (int r = 0; r < 4; ++r) il[r] = __shfl(linv, lhi * 4 + r);
  const int t0 = q0 + w * 16 + lhi * 4;
#pragma unroll
  for (int r = 0; r < 4; ++r) {
    size_t rowb = (size_t)(b * TB + t0 + r) * 1536;
#pragma unroll
    for (int nt = 0; nt < 4; ++nt) {
      float o = oacc[nt][r] * il[r];
      ushort hi = f2bf(o);
      ushort lo = f2bf(o - bf2f(hi));
      int c = h * DH + nt * 16 + llo;
      Ap[rowb + c] = hi;
      Ap[rowb + 512 + c] = lo;
      Ap[rowb + 1024 + c] = hi;
    }
  }
}

// ---------------------------------------------------------------------------
extern "C" void kernel_launch(void* const* d_in, const int* in_sizes, int n_in,
                              void* d_out, int out_size, void* d_ws,
                              size_t ws_size, hipStream_t stream) {
  (void)in_sizes; (void)n_in; (void)out_size; (void)ws_size;
  const float* q = (const float*)d_in[0];
  const float* k = (const float*)d_in[1];
  const float* v = (const float*)d_in[2];
  const void* pm = d_in[3];
  const float* Wq = (const float*)d_in[4];
  const float* bq = (const float*)d_in[5];
  const float* Wk = (const float*)d_in[6];
  const float* bk = (const float*)d_in[7];
  const float* Wv = (const float*)d_in[8];
  const float* bv = (const float*)d_in[9];
  const float* Wo = (const float*)d_in[10];
  const float* bo = (const float*)d_in[11];

  char* ws = (char*)d_ws;
  const size_t MB = (size_t)1 << 20;
  // [0,24MB): A' (attention output, split-bf16 rows)
  ushort* Ap = (ushort*)(ws);
  // [24,25.5MB): Wall = [Wq^T | Wk^T | Wv^T] bf16
  ushort* Wall = (ushort*)(ws + 24 * MB);
  // [26,27.5MB): split O-weight
  ushort* Wot = (ushort*)(ws + 26 * MB);
  // [32,56MB): fragment-linear Q/K/V (8MB sections)
  ushort* Qh = (ushort*)(ws + 32 * MB);
  float* mbias = (float*)(ws + 56 * MB);
  int* mode = (int*)(ws + 56 * MB + 40960);

  mask_detect_kernel<<<1, 256, 0, stream>>>((const unsigned char*)pm, mode);
  mask_build_kernel<<<32, 256, 0, stream>>>(pm, mode, mbias);

  wtrans3_kernel<<<dim3(8, 8, 3), 256, 0, stream>>>(Wq, Wk, Wv, Wall);
  wtrans_split_kernel<<<dim3(8, 8), 256, 0, stream>>>(Wo, Wot);

  // Q scale folds 1/sqrt(64) * log2(e) for the exp2-domain softmax
  const float qscale = 0.125f * 1.4426950408889634f;
  projqkv_kernel<<<12288, 64, 0, stream>>>(q, k, v, Wall,
                                           bq, bk, bv, Qh, qscale);

  attn_mfma_kernel<<<1024, 256, 0, stream>>>(
      Qh, Qh + ((size_t)4 << 20), Qh + ((size_t)8 << 20), mbias, Ap);

  projo_kernel<<<4096, 64, 0, stream>>>(Ap, Wot, bo, (float*)d_out);
}

// Round 11
// 163.055 us; speedup vs baseline: 1.9992x; 1.9971x over previous
//
#include <hip/hip_runtime.h>
#include <hip/hip_bf16.h>
#include <math.h>

// MultiHeadAttention  B=4, T=2048, D=512, H=8, DH=64, fp32 in/out.
// R11: projections rewritten as 4-wave 128-tile LDS GEMMs (m93-style:
// double-buffered LDS, BK=32, 2-phase pipeline, 16 MFMA : 8 ds_read per
// wave-step). Fragment-linear epilogue scatter verbatim from verified R8.
// Attention byte-identical to R8/R9/R10 (98us).

#define TB 2048
#define DD 512
#define NH 8
#define DH 64

typedef short bf16x8 __attribute__((ext_vector_type(8)));
typedef float f32x4 __attribute__((ext_vector_type(4)));

static __device__ __forceinline__ ushort f2bf(float x) {
  __hip_bfloat16 h = __float2bfloat16(x);
  return *reinterpret_cast<ushort*>(&h);
}
static __device__ __forceinline__ float bf2f(ushort u) {
  unsigned int v = ((unsigned int)u) << 16;
  return __uint_as_float(v);
}
static __device__ __forceinline__ float fast_exp2(float x) {
  return __builtin_amdgcn_exp2f(x);  // v_exp_f32: D = 2^S0
}
// pack2(x,y): low16 = bf16(x), high16 = bf16(y), round-half-up (R8-verified)
static __device__ __forceinline__ unsigned pack2(float x, float y) {
  return __builtin_amdgcn_perm(__float_as_uint(y) + 0x8000u,
                               __float_as_uint(x) + 0x8000u, 0x07060302u);
}
static __device__ __forceinline__ bf16x8 cvt8(float4 lo, float4 hi) {
  union { unsigned u[4]; bf16x8 v; } r;
  r.u[0] = pack2(lo.x, lo.y);
  r.u[1] = pack2(lo.z, lo.w);
  r.u[2] = pack2(hi.x, hi.y);
  r.u[3] = pack2(hi.z, hi.w);
  return r.v;
}

// ---------------------------------------------------------------------------
// Mask canonicalization (verified R1-R10). Output: float bias 0 / -inf.
__global__ void mask_detect_kernel(const unsigned char* __restrict__ m,
                                   int* __restrict__ mode) {
  __shared__ int c1, c2;
  if (threadIdx.x == 0) { c1 = 0; c2 = 0; }
  __syncthreads();
  int l1 = 0, l2 = 0;
  for (int i = threadIdx.x; i < 8192; i += blockDim.x) {
    int ph = i & 3;
    unsigned char v = m[i];
    if (ph == 1 && v) l1++;
    if (ph == 2 && v) l2++;
  }
  if (l1) atomicAdd(&c1, l1);
  if (l2) atomicAdd(&c2, l2);
  __syncthreads();
  if (threadIdx.x == 0) *mode = (c1 > 0) ? 0 : ((c2 > 0) ? 1 : 2);
}

__global__ void mask_build_kernel(const void* __restrict__ m,
                                  const int* __restrict__ mode,
                                  float* __restrict__ out) {
  int i = blockIdx.x * blockDim.x + threadIdx.x;
  int md = *mode;
  int v;
  if (md == 0)      v = ((const unsigned char*)m)[i] != 0;
  else if (md == 1) v = ((const float*)m)[i] != 0.0f;
  else              v = ((const int*)m)[i] != 0;
  out[i] = v ? 0.0f : -INFINITY;
}

// ---------------------------------------------------------------------------
// W [K][N] f32 -> Wt [N][K] bf16, 3 sections (z = Q/K/V).
__global__ __launch_bounds__(256) void wtrans3_kernel(
    const float* __restrict__ Wq, const float* __restrict__ Wk,
    const float* __restrict__ Wv, ushort* __restrict__ Wall) {
  __shared__ ushort t[64][68];
  const float* W = (blockIdx.z == 0) ? Wq : (blockIdx.z == 1) ? Wk : Wv;
  ushort* Wt = Wall + (size_t)blockIdx.z * (512 * 512);
  const int bn = blockIdx.x << 6, bk = blockIdx.y << 6;
  const int tx = threadIdx.x & 15, ty = threadIdx.x >> 4;
#pragma unroll
  for (int rr = 0; rr < 64; rr += 16) {
    float4 v = *(const float4*)&W[(size_t)(bk + rr + ty) * DD + bn + (tx << 2)];
    t[(tx << 2) + 0][rr + ty] = f2bf(v.x);
    t[(tx << 2) + 1][rr + ty] = f2bf(v.y);
    t[(tx << 2) + 2][rr + ty] = f2bf(v.z);
    t[(tx << 2) + 3][rr + ty] = f2bf(v.w);
  }
  __syncthreads();
#pragma unroll
  for (int rr = 0; rr < 64; rr += 16) {
    ushort4 o;
    o.x = t[rr + ty][(tx << 2) + 0];
    o.y = t[rr + ty][(tx << 2) + 1];
    o.z = t[rr + ty][(tx << 2) + 2];
    o.w = t[rr + ty][(tx << 2) + 3];
    *(ushort4*)&Wt[(size_t)(bn + rr + ty) * DD + bk + (tx << 2)] = o;
  }
}

// ---------------------------------------------------------------------------
// Wo [K][N] f32 -> Wt' [N][1536]: sections [Whi | Whi | Wlo] (split-bf16).
__global__ __launch_bounds__(256) void wtrans_split_kernel(
    const float* __restrict__ W, ushort* __restrict__ Wt) {
  __shared__ ushort thi[64][68];
  __shared__ ushort tlo[64][68];
  const int bn = blockIdx.x << 6, bk = blockIdx.y << 6;
  const int tx = threadIdx.x & 15, ty = threadIdx.x >> 4;
#pragma unroll
  for (int rr = 0; rr < 64; rr += 16) {
    float4 v = *(const float4*)&W[(size_t)(bk + rr + ty) * DD + bn + (tx << 2)];
    float vv[4] = {v.x, v.y, v.z, v.w};
#pragma unroll
    for (int c = 0; c < 4; ++c) {
      ushort hi = f2bf(vv[c]);
      ushort lo = f2bf(vv[c] - bf2f(hi));
      thi[(tx << 2) + c][rr + ty] = hi;
      tlo[(tx << 2) + c][rr + ty] = lo;
    }
  }
  __syncthreads();
#pragma unroll
  for (int rr = 0; rr < 64; rr += 16) {
    ushort4 h4, l4;
    h4.x = thi[rr + ty][(tx << 2) + 0];
    h4.y = thi[rr + ty][(tx << 2) + 1];
    h4.z = thi[rr + ty][(tx << 2) + 2];
    h4.w = thi[rr + ty][(tx << 2) + 3];
    l4.x = tlo[rr + ty][(tx << 2) + 0];
    l4.y = tlo[rr + ty][(tx << 2) + 1];
    l4.z = tlo[rr + ty][(tx << 2) + 2];
    l4.w = tlo[rr + ty][(tx << 2) + 3];
    size_t rowb = (size_t)(bn + rr + ty) * 1536;
    *(ushort4*)&Wt[rowb + bk + (tx << 2)] = h4;         // sec0: Whi
    *(ushort4*)&Wt[rowb + 512 + bk + (tx << 2)] = h4;   // sec1: Whi
    *(ushort4*)&Wt[rowb + 1024 + bk + (tx << 2)] = l4;  // sec2: Wlo
  }
}

// ---------------------------------------------------------------------------
// Fused QKV projection, 4-wave 128x128-tile LDS GEMM, f32 inputs.
// 768 blocks (XCD-grouped: 4 n-blocks sharing an A-tile share bid%8).
// Per K-step(32): stage next tile (reg->cvt->LDS dbuf), 8 ds_read_b128 +
// 16 MFMA per wave. Epilogue: fragment-linear scatter (verbatim R8).
__global__ __launch_bounds__(256) void projqkv_kernel(
    const float* __restrict__ Qx, const float* __restrict__ Kx,
    const float* __restrict__ Vx, const ushort* __restrict__ Wall,
    const float* __restrict__ bq, const float* __restrict__ bk,
    const float* __restrict__ bv, ushort* __restrict__ Yall, float qscale) {
  __shared__ __align__(16) ushort As[2][128][32];
  __shared__ __align__(16) ushort Bs[2][128][32];

  const int tid = threadIdx.x;
  const int w = tid >> 6, lane = tid & 63;
  const int llo = lane & 15, lhi = lane >> 4;
  const int wm = w >> 1, wn = w & 1;

  // swizzled bid -> (sec, m-tile, n-tile); same-A blocks share bid%8 (XCD)
  const int bid = blockIdx.x;
  const int x = bid & 7, rest = bid >> 3;
  const int ni = rest & 3;
  const int gg = (rest >> 2) * 8 + x;  // 0..191
  const int sec = gg >> 6;             // 0=Q,1=K,2=V
  const int mt = gg & 63;
  const int m0 = mt << 7;
  const int n0s = ni << 7;             // col base within section

  const float* A = (sec == 0) ? Qx : (sec == 1) ? Kx : Vx;
  const float* bias = (sec == 0) ? bq : (sec == 1) ? bk : bv;
  const float scale = (sec == 0) ? qscale : 1.0f;
  const ushort* Wt = Wall + (size_t)(sec * 512 + n0s) * DD;  // 128 rows x 512

  // staging: thread covers half a row (16 elems) of the 128x32 tile
  const int srow = tid >> 1, scol = (tid & 1) << 4;
  const float* Ag = A + (size_t)(m0 + srow) * DD + scol;
  const ushort* Bg = Wt + (size_t)srow * DD + scol;

  f32x4 acc[4][4];
#pragma unroll
  for (int mi = 0; mi < 4; ++mi)
#pragma unroll
    for (int nj = 0; nj < 4; ++nj) acc[mi][nj] = (f32x4){0.f, 0.f, 0.f, 0.f};

  // prologue: stage k-step 0 into buf 0
  {
    float4 f0 = *(const float4*)(Ag + 0);
    float4 f1 = *(const float4*)(Ag + 4);
    float4 f2 = *(const float4*)(Ag + 8);
    float4 f3 = *(const float4*)(Ag + 12);
    bf16x8 w0 = *(const bf16x8*)(Bg + 0);
    bf16x8 w1 = *(const bf16x8*)(Bg + 8);
    *(bf16x8*)&As[0][srow][scol] = cvt8(f0, f1);
    *(bf16x8*)&As[0][srow][scol + 8] = cvt8(f2, f3);
    *(bf16x8*)&Bs[0][srow][scol] = w0;
    *(bf16x8*)&Bs[0][srow][scol + 8] = w1;
  }
  __syncthreads();

  int cur = 0;
  for (int t = 0; t < 16; ++t) {
    float4 f0, f1, f2, f3;
    bf16x8 w0, w1;
    if (t < 15) {  // issue next-tile global loads (land during MFMA below)
      const float* ag = Ag + (t + 1) * 32;
      const ushort* bg = Bg + (t + 1) * 32;
      f0 = *(const float4*)(ag + 0);
      f1 = *(const float4*)(ag + 4);
      f2 = *(const float4*)(ag + 8);
      f3 = *(const float4*)(ag + 12);
      w0 = *(const bf16x8*)(bg + 0);
      w1 = *(const bf16x8*)(bg + 8);
    }
    bf16x8 af[4], bfr[4];
#pragma unroll
    for (int mi = 0; mi < 4; ++mi)
      af[mi] = *(const bf16x8*)&As[cur][wm * 64 + mi * 16 + llo][lhi * 8];
#pragma unroll
    for (int nj = 0; nj < 4; ++nj)
      bfr[nj] = *(const bf16x8*)&Bs[cur][wn * 64 + nj * 16 + llo][lhi * 8];
    __builtin_amdgcn_s_setprio(1);
#pragma unroll
    for (int mi = 0; mi < 4; ++mi)
#pragma unroll
      for (int nj = 0; nj < 4; ++nj)
        acc[mi][nj] = __builtin_amdgcn_mfma_f32_16x16x32_bf16(
            af[mi], bfr[nj], acc[mi][nj], 0, 0, 0);
    __builtin_amdgcn_s_setprio(0);
    if (t < 15) {
      *(bf16x8*)&As[cur ^ 1][srow][scol] = cvt8(f0, f1);
      *(bf16x8*)&As[cur ^ 1][srow][scol + 8] = cvt8(f2, f3);
      *(bf16x8*)&Bs[cur ^ 1][srow][scol] = w0;
      *(bf16x8*)&Bs[cur ^ 1][srow][scol + 8] = w1;
    }
    __syncthreads();
    cur ^= 1;
  }

  // epilogue: fragment-linear scatter (formulas verbatim from verified R8)
  float bb[4];
#pragma unroll
  for (int nj = 0; nj < 4; ++nj)
    bb[nj] = bias[n0s + wn * 64 + nj * 16 + llo];

  ushort* Yq = Yall;
  ushort* Yk = Yall + ((size_t)4 << 20);
  ushort* Yv = Yall + ((size_t)8 << 20);
#pragma unroll
  for (int mi = 0; mi < 4; ++mi)
#pragma unroll
    for (int nj = 0; nj < 4; ++nj) {
      int colS = n0s + wn * 64 + nj * 16 + llo;
      int h = colS >> 6, dh = colS & (DH - 1);
#pragma unroll
      for (int r = 0; r < 4; ++r) {
        int row = m0 + wm * 64 + mi * 16 + lhi * 4 + r;
        int bidx = row >> 11, t = row & (TB - 1);
        int bh = bidx * NH + h;
        ushort u = f2bf((acc[mi][nj][r] + bb[nj]) * scale);
        if (sec == 0) {
          Yq[((size_t)(bh * 128 + (t >> 4)) * 2 + (dh >> 5)) * 512 +
             ((((dh >> 3) & 3) << 4) + (t & 15)) * 8 + (dh & 7)] = u;
        } else if (sec == 1) {
          Yk[((size_t)(bh * 32 + (t >> 6)) << 12) +
             (((dh >> 5) << 2) + ((t >> 4) & 3)) * 512 +
             ((((dh >> 3) & 3) << 4) + (t & 15)) * 8 + (dh & 7)] = u;
        } else {
          Yv[((size_t)(bh * 32 + (t >> 6)) << 12) +
             ((((t >> 5) & 1) << 2) + (dh >> 4)) * 512 +
             ((((t >> 3) & 3) << 4) + (dh & 15)) * 8 + (t & 7)] = u;
        }
      }
    }
}

// ---------------------------------------------------------------------------
// O-projection, 4-wave 128x64-tile LDS GEMM. A'[8192][1536] split-bf16 @
// Wot[512][1536] -> f32 + bias. 512 blocks, K=1536 (48 steps), dbuf LDS.
__global__ __launch_bounds__(256) void projo_kernel(
    const ushort* __restrict__ A, const ushort* __restrict__ Wt,
    const float* __restrict__ bias, float* __restrict__ Y) {
  __shared__ __align__(16) ushort As[2][128][32];
  __shared__ __align__(16) ushort Bs[2][64][32];

  const int tid = threadIdx.x;
  const int w = tid >> 6, lane = tid & 63;
  const int llo = lane & 15, lhi = lane >> 4;
  const int wm = w >> 1, wn = w & 1;

  // swizzled bid: 8 n-blocks sharing an A'-tile share bid%8 (XCD)
  const int bid = blockIdx.x;
  const int x = bid & 7, rest = bid >> 3;
  const int ni = rest & 7;
  const int mt = (rest >> 3) * 8 + x;  // 0..63
  const int m0 = mt << 7;
  const int n0 = ni << 6;
  const int K = 1536;

  // staging: A' 128x32 (2x16B/thread), B 64x32 (1x16B/thread)
  const int arow = tid >> 1, acol = (tid & 1) << 4;
  const int brow = tid >> 2, bcol = (tid & 3) << 3;
  const ushort* Ag = A + (size_t)(m0 + arow) * K + acol;
  const ushort* Bg = Wt + (size_t)(n0 + brow) * K + bcol;

  f32x4 acc[4][2];
#pragma unroll
  for (int mi = 0; mi < 4; ++mi)
#pragma unroll
    for (int nj = 0; nj < 2; ++nj) acc[mi][nj] = (f32x4){0.f, 0.f, 0.f, 0.f};

  {
    bf16x8 a0 = *(const bf16x8*)(Ag + 0);
    bf16x8 a1 = *(const bf16x8*)(Ag + 8);
    bf16x8 b0 = *(const bf16x8*)(Bg + 0);
    *(bf16x8*)&As[0][arow][acol] = a0;
    *(bf16x8*)&As[0][arow][acol + 8] = a1;
    *(bf16x8*)&Bs[0][brow][bcol] = b0;
  }
  __syncthreads();

  int cur = 0;
#pragma unroll 2
  for (int t = 0; t < 48; ++t) {
    bf16x8 a0, a1, b0;
    if (t < 47) {
      const ushort* ag = Ag + (t + 1) * 32;
      const ushort* bg = Bg + (t + 1) * 32;
      a0 = *(const bf16x8*)(ag + 0);
      a1 = *(const bf16x8*)(ag + 8);
      b0 = *(const bf16x8*)(bg + 0);
    }
    bf16x8 af[4], bfr[2];
#pragma unroll
    for (int mi = 0; mi < 4; ++mi)
      af[mi] = *(const bf16x8*)&As[cur][wm * 64 + mi * 16 + llo][lhi * 8];
#pragma unroll
    for (int nj = 0; nj < 2; ++nj)
      bfr[nj] = *(const bf16x8*)&Bs[cur][wn * 32 + nj * 16 + llo][lhi * 8];
    __builtin_amdgcn_s_setprio(1);
#pragma unroll
    for (int mi = 0; mi < 4; ++mi)
#pragma unroll
      for (int nj = 0; nj < 2; ++nj)
        acc[mi][nj] = __builtin_amdgcn_mfma_f32_16x16x32_bf16(
            af[mi], bfr[nj], acc[mi][nj], 0, 0, 0);
    __builtin_amdgcn_s_setprio(0);
    if (t < 47) {
      *(bf16x8*)&As[cur ^ 1][arow][acol] = a0;
      *(bf16x8*)&As[cur ^ 1][arow][acol + 8] = a1;
      *(bf16x8*)&Bs[cur ^ 1][brow][bcol] = b0;
    }
    __syncthreads();
    cur ^= 1;
  }

  float bb[2];
#pragma unroll
  for (int nj = 0; nj < 2; ++nj)
    bb[nj] = bias[n0 + wn * 32 + nj * 16 + llo];
#pragma unroll
  for (int mi = 0; mi < 4; ++mi)
#pragma unroll
    for (int nj = 0; nj < 2; ++nj) {
      int col = n0 + wn * 32 + nj * 16 + llo;
#pragma unroll
      for (int r = 0; r < 4; ++r) {
        int row = m0 + wm * 64 + mi * 16 + lhi * 4 + r;
        Y[(size_t)row * DD + col] = acc[mi][nj][r] + bb[nj];
      }
    }
}

// ---------------------------------------------------------------------------
// Swapped-QK^T bf16 MFMA flash attention, fragment-linear operands.
// UNCHANGED from R8/R9/R10 (verified: 98us, MfmaUtil 14.5%).
__global__ __launch_bounds__(256) void attn_mfma_kernel(
    const ushort* __restrict__ Qf,    // frag-linear, scaled 0.125*log2e
    const ushort* __restrict__ Kf,    // frag-linear
    const ushort* __restrict__ Vf,    // frag-linear (V^T frags)
    const float* __restrict__ mbias,  // [B][T] 0 / -inf
    ushort* __restrict__ Ap) {        // A' [8192][1536]
  __shared__ __align__(16) ushort Plds[4][16][72];

  const int tid = threadIdx.x;
  const int w = tid >> 6, lane = tid & 63;
  const int lhi = lane >> 4, llo = lane & 15;
  const int lane8 = lane * 8;

  const int bid = blockIdx.x;
  const int j = bid >> 3;
  const int bh = (bid & 7) + ((j >> 5) << 3);  // same-bh blocks -> same XCD
  const int qt = j & 31;
  const int b = bh >> 3, h = bh & 7;
  const int q0 = qt << 6;

  const float* mb = mbias + b * TB;
  ushort* pl = &Plds[w][0][0];  // [16][72]

  const ushort* Qb = Qf + ((size_t)((bh << 7) + (q0 >> 4) + w) * 2) * 512 + lane8;
  bf16x8 qa0 = *(const bf16x8*)Qb;
  bf16x8 qa1 = *(const bf16x8*)(Qb + 512);

  const size_t bhK = (size_t)bh << 5;
  f32x4 oacc[4];
#pragma unroll
  for (int nt = 0; nt < 4; ++nt) oacc[nt] = (f32x4){0.f, 0.f, 0.f, 0.f};
  float m = -INFINITY, l = 0.f;

  for (int kt64 = 0; kt64 < 32; ++kt64) {
    const ushort* Kt = Kf + ((bhK + kt64) << 12) + lane8;
    const ushort* Vt = Vf + ((bhK + kt64) << 12) + lane8;
    bf16x8 kf[8];
#pragma unroll
    for (int i = 0; i < 8; ++i) kf[i] = *(const bf16x8*)(Kt + i * 512);
    bf16x8 vf[8];
#pragma unroll
    for (int i = 0; i < 8; ++i) vf[i] = *(const bf16x8*)(Vt + i * 512);
    float4 mb4[4];
#pragma unroll
    for (int nt = 0; nt < 4; ++nt)
      mb4[nt] = *(const float4*)&mb[kt64 * 64 + nt * 16 + lhi * 4];

    f32x4 s[4];
    __builtin_amdgcn_s_setprio(1);
#pragma unroll
    for (int nt = 0; nt < 4; ++nt) {
      s[nt] = (f32x4){0.f, 0.f, 0.f, 0.f};
      s[nt] = __builtin_amdgcn_mfma_f32_16x16x32_bf16(kf[nt], qa0, s[nt], 0, 0, 0);
      s[nt] = __builtin_amdgcn_mfma_f32_16x16x32_bf16(kf[4 + nt], qa1, s[nt], 0, 0, 0);
    }
    __builtin_amdgcn_s_setprio(0);

#pragma unroll
    for (int nt = 0; nt < 4; ++nt) {
      s[nt][0] += mb4[nt].x;
      s[nt][1] += mb4[nt].y;
      s[nt][2] += mb4[nt].z;
      s[nt][3] += mb4[nt].w;
    }

    float mx[4];
#pragma unroll
    for (int nt = 0; nt < 4; ++nt)
      mx[nt] = fmaxf(fmaxf(s[nt][0], s[nt][1]), fmaxf(s[nt][2], s[nt][3]));
    float pmax = fmaxf(fmaxf(mx[0], mx[1]), fmaxf(mx[2], mx[3]));
    pmax = fmaxf(pmax, __shfl_xor(pmax, 16));
    pmax = fmaxf(pmax, __shfl_xor(pmax, 32));

    if (__any(pmax > m + 8.f)) {
      float newm = fmaxf(m, pmax);
      float alpha = fast_exp2(m - newm);
      float al[4];
#pragma unroll
      for (int r = 0; r < 4; ++r) al[r] = __shfl(alpha, lhi * 4 + r);
#pragma unroll
      for (int nt = 0; nt < 4; ++nt) {
        oacc[nt][0] *= al[0];
        oacc[nt][1] *= al[1];
        oacc[nt][2] *= al[2];
        oacc[nt][3] *= al[3];
      }
      l *= alpha;
      m = newm;
    }

#pragma unroll
    for (int nt = 0; nt < 4; ++nt)
#pragma unroll
      for (int r = 0; r < 4; ++r) s[nt][r] = fast_exp2(s[nt][r] - m);
    float sm[4];
#pragma unroll
    for (int nt = 0; nt < 4; ++nt)
      sm[nt] = (s[nt][0] + s[nt][1]) + (s[nt][2] + s[nt][3]);
    float rsum = (sm[0] + sm[1]) + (sm[2] + sm[3]);
    if (__any(m == -INFINITY)) {
      if (m == -INFINITY) {
        rsum = 0.f;
#pragma unroll
        for (int nt = 0; nt < 4; ++nt) s[nt] = (f32x4){0.f, 0.f, 0.f, 0.f};
      }
    }
    rsum += __shfl_xor(rsum, 16);
    rsum += __shfl_xor(rsum, 32);
    l += rsum;

#pragma unroll
    for (int nt = 0; nt < 4; ++nt) {
      unsigned int lo = pack2(s[nt][0], s[nt][1]);
      unsigned int hi = pack2(s[nt][2], s[nt][3]);
      *(uint2*)&pl[llo * 72 + nt * 16 + lhi * 4] = make_uint2(lo, hi);
    }

    __builtin_amdgcn_s_setprio(1);
#pragma unroll
    for (int kc = 0; kc < 2; ++kc) {
      bf16x8 pa = *(const bf16x8*)&pl[llo * 72 + kc * 32 + lhi * 8];
#pragma unroll
      for (int nt = 0; nt < 4; ++nt)
        oacc[nt] = __builtin_amdgcn_mfma_f32_16x16x32_bf16(pa, vf[kc * 4 + nt], oacc[nt], 0, 0, 0);
    }
    __builtin_amdgcn_s_setprio(0);
  }

  float linv = (l > 0.f) ? 1.f / l : 0.f;
  float il[4];
#pragma unroll
  for (int r = 0; r < 4; ++r) il[r] = __shfl(linv, lhi * 4 + r);
  const int t0 = q0 + w * 16 + lhi * 4;
#pragma unroll
  for (int r = 0; r < 4; ++r) {
    size_t rowb = (size_t)(b * TB + t0 + r) * 1536;
#pragma unroll
    for (int nt = 0; nt < 4; ++nt) {
      float o = oacc[nt][r] * il[r];
      ushort hi = f2bf(o);
      ushort lo = f2bf(o - bf2f(hi));
      int c = h * DH + nt * 16 + llo;
      Ap[rowb + c] = hi;
      Ap[rowb + 512 + c] = lo;
      Ap[rowb + 1024 + c] = hi;
    }
  }
}

// ---------------------------------------------------------------------------
extern "C" void kernel_launch(void* const* d_in, const int* in_sizes, int n_in,
                              void* d_out, int out_size, void* d_ws,
                              size_t ws_size, hipStream_t stream) {
  (void)in_sizes; (void)n_in; (void)out_size; (void)ws_size;
  const float* q = (const float*)d_in[0];
  const float* k = (const float*)d_in[1];
  const float* v = (const float*)d_in[2];
  const void* pm = d_in[3];
  const float* Wq = (const float*)d_in[4];
  const float* bq = (const float*)d_in[5];
  const float* Wk = (const float*)d_in[6];
  const float* bk = (const float*)d_in[7];
  const float* Wv = (const float*)d_in[8];
  const float* bv = (const float*)d_in[9];
  const float* Wo = (const float*)d_in[10];
  const float* bo = (const float*)d_in[11];

  char* ws = (char*)d_ws;
  const size_t MB = (size_t)1 << 20;
  // [0,24MB): A' (attention output, split-bf16 rows)
  ushort* Ap = (ushort*)(ws);
  // [24,25.5MB): Wall = [Wq^T | Wk^T | Wv^T] bf16
  ushort* Wall = (ushort*)(ws + 24 * MB);
  // [26,27.5MB): split O-weight
  ushort* Wot = (ushort*)(ws + 26 * MB);
  // [32,56MB): fragment-linear Q/K/V (8MB sections)
  ushort* Qh = (ushort*)(ws + 32 * MB);
  float* mbias = (float*)(ws + 56 * MB);
  int* mode = (int*)(ws + 56 * MB + 40960);

  mask_detect_kernel<<<1, 256, 0, stream>>>((const unsigned char*)pm, mode);
  mask_build_kernel<<<32, 256, 0, stream>>>(pm, mode, mbias);

  wtrans3_kernel<<<dim3(8, 8, 3), 256, 0, stream>>>(Wq, Wk, Wv, Wall);
  wtrans_split_kernel<<<dim3(8, 8), 256, 0, stream>>>(Wo, Wot);

  // Q scale folds 1/sqrt(64) * log2(e) for the exp2-domain softmax
  const float qscale = 0.125f * 1.4426950408889634f;
  projqkv_kernel<<<768, 256, 0, stream>>>(q, k, v, Wall,
                                          bq, bk, bv, Qh, qscale);

  attn_mfma_kernel<<<1024, 256, 0, stream>>>(
      Qh, Qh + ((size_t)4 << 20), Qh + ((size_t)8 << 20), mbias, Ap);

  projo_kernel<<<512, 256, 0, stream>>>(Ap, Wot, bo, (float*)d_out);
}

// Round 12
// 159.782 us; speedup vs baseline: 2.0401x; 1.0205x over previous
//
#include <hip/hip_runtime.h>
#include <hip/hip_bf16.h>
#include <math.h>

// MultiHeadAttention  B=4, T=2048, D=512, H=8, DH=64, fp32 in/out.
// R12: attn chain cuts — cross-tile K register prefetch (R5-style) +
// deferred cross-lane reductions (lane-local trigger test, per-lane partial
// l reduced once in epilogue; common path has ZERO shuffles/tile).
// Projections byte-identical to R11 (4-wave LDS GEMMs, verified).

#define TB 2048
#define DD 512
#define NH 8
#define DH 64

typedef short bf16x8 __attribute__((ext_vector_type(8)));
typedef float f32x4 __attribute__((ext_vector_type(4)));

static __device__ __forceinline__ ushort f2bf(float x) {
  __hip_bfloat16 h = __float2bfloat16(x);
  return *reinterpret_cast<ushort*>(&h);
}
static __device__ __forceinline__ float bf2f(ushort u) {
  unsigned int v = ((unsigned int)u) << 16;
  return __uint_as_float(v);
}
static __device__ __forceinline__ float fast_exp2(float x) {
  return __builtin_amdgcn_exp2f(x);  // v_exp_f32: D = 2^S0
}
// pack2(x,y): low16 = bf16(x), high16 = bf16(y), round-half-up (R8-verified)
static __device__ __forceinline__ unsigned pack2(float x, float y) {
  return __builtin_amdgcn_perm(__float_as_uint(y) + 0x8000u,
                               __float_as_uint(x) + 0x8000u, 0x07060302u);
}
static __device__ __forceinline__ bf16x8 cvt8(float4 lo, float4 hi) {
  union { unsigned u[4]; bf16x8 v; } r;
  r.u[0] = pack2(lo.x, lo.y);
  r.u[1] = pack2(lo.z, lo.w);
  r.u[2] = pack2(hi.x, hi.y);
  r.u[3] = pack2(hi.z, hi.w);
  return r.v;
}

// ---------------------------------------------------------------------------
// Mask canonicalization (verified R1-R11). Output: float bias 0 / -inf.
__global__ void mask_detect_kernel(const unsigned char* __restrict__ m,
                                   int* __restrict__ mode) {
  __shared__ int c1, c2;
  if (threadIdx.x == 0) { c1 = 0; c2 = 0; }
  __syncthreads();
  int l1 = 0, l2 = 0;
  for (int i = threadIdx.x; i < 8192; i += blockDim.x) {
    int ph = i & 3;
    unsigned char v = m[i];
    if (ph == 1 && v) l1++;
    if (ph == 2 && v) l2++;
  }
  if (l1) atomicAdd(&c1, l1);
  if (l2) atomicAdd(&c2, l2);
  __syncthreads();
  if (threadIdx.x == 0) *mode = (c1 > 0) ? 0 : ((c2 > 0) ? 1 : 2);
}

__global__ void mask_build_kernel(const void* __restrict__ m,
                                  const int* __restrict__ mode,
                                  float* __restrict__ out) {
  int i = blockIdx.x * blockDim.x + threadIdx.x;
  int md = *mode;
  int v;
  if (md == 0)      v = ((const unsigned char*)m)[i] != 0;
  else if (md == 1) v = ((const float*)m)[i] != 0.0f;
  else              v = ((const int*)m)[i] != 0;
  out[i] = v ? 0.0f : -INFINITY;
}

// ---------------------------------------------------------------------------
// W [K][N] f32 -> Wt [N][K] bf16, 3 sections (z = Q/K/V).
__global__ __launch_bounds__(256) void wtrans3_kernel(
    const float* __restrict__ Wq, const float* __restrict__ Wk,
    const float* __restrict__ Wv, ushort* __restrict__ Wall) {
  __shared__ ushort t[64][68];
  const float* W = (blockIdx.z == 0) ? Wq : (blockIdx.z == 1) ? Wk : Wv;
  ushort* Wt = Wall + (size_t)blockIdx.z * (512 * 512);
  const int bn = blockIdx.x << 6, bk = blockIdx.y << 6;
  const int tx = threadIdx.x & 15, ty = threadIdx.x >> 4;
#pragma unroll
  for (int rr = 0; rr < 64; rr += 16) {
    float4 v = *(const float4*)&W[(size_t)(bk + rr + ty) * DD + bn + (tx << 2)];
    t[(tx << 2) + 0][rr + ty] = f2bf(v.x);
    t[(tx << 2) + 1][rr + ty] = f2bf(v.y);
    t[(tx << 2) + 2][rr + ty] = f2bf(v.z);
    t[(tx << 2) + 3][rr + ty] = f2bf(v.w);
  }
  __syncthreads();
#pragma unroll
  for (int rr = 0; rr < 64; rr += 16) {
    ushort4 o;
    o.x = t[rr + ty][(tx << 2) + 0];
    o.y = t[rr + ty][(tx << 2) + 1];
    o.z = t[rr + ty][(tx << 2) + 2];
    o.w = t[rr + ty][(tx << 2) + 3];
    *(ushort4*)&Wt[(size_t)(bn + rr + ty) * DD + bk + (tx << 2)] = o;
  }
}

// ---------------------------------------------------------------------------
// Wo [K][N] f32 -> Wt' [N][1536]: sections [Whi | Whi | Wlo] (split-bf16).
__global__ __launch_bounds__(256) void wtrans_split_kernel(
    const float* __restrict__ W, ushort* __restrict__ Wt) {
  __shared__ ushort thi[64][68];
  __shared__ ushort tlo[64][68];
  const int bn = blockIdx.x << 6, bk = blockIdx.y << 6;
  const int tx = threadIdx.x & 15, ty = threadIdx.x >> 4;
#pragma unroll
  for (int rr = 0; rr < 64; rr += 16) {
    float4 v = *(const float4*)&W[(size_t)(bk + rr + ty) * DD + bn + (tx << 2)];
    float vv[4] = {v.x, v.y, v.z, v.w};
#pragma unroll
    for (int c = 0; c < 4; ++c) {
      ushort hi = f2bf(vv[c]);
      ushort lo = f2bf(vv[c] - bf2f(hi));
      thi[(tx << 2) + c][rr + ty] = hi;
      tlo[(tx << 2) + c][rr + ty] = lo;
    }
  }
  __syncthreads();
#pragma unroll
  for (int rr = 0; rr < 64; rr += 16) {
    ushort4 h4, l4;
    h4.x = thi[rr + ty][(tx << 2) + 0];
    h4.y = thi[rr + ty][(tx << 2) + 1];
    h4.z = thi[rr + ty][(tx << 2) + 2];
    h4.w = thi[rr + ty][(tx << 2) + 3];
    l4.x = tlo[rr + ty][(tx << 2) + 0];
    l4.y = tlo[rr + ty][(tx << 2) + 1];
    l4.z = tlo[rr + ty][(tx << 2) + 2];
    l4.w = tlo[rr + ty][(tx << 2) + 3];
    size_t rowb = (size_t)(bn + rr + ty) * 1536;
    *(ushort4*)&Wt[rowb + bk + (tx << 2)] = h4;         // sec0: Whi
    *(ushort4*)&Wt[rowb + 512 + bk + (tx << 2)] = h4;   // sec1: Whi
    *(ushort4*)&Wt[rowb + 1024 + bk + (tx << 2)] = l4;  // sec2: Wlo
  }
}

// ---------------------------------------------------------------------------
// Fused QKV projection, 4-wave 128x128-tile LDS GEMM, f32 inputs.
// (verified R11: XCD-grouped, dbuf LDS, frag-linear epilogue from R8)
__global__ __launch_bounds__(256) void projqkv_kernel(
    const float* __restrict__ Qx, const float* __restrict__ Kx,
    const float* __restrict__ Vx, const ushort* __restrict__ Wall,
    const float* __restrict__ bq, const float* __restrict__ bk,
    const float* __restrict__ bv, ushort* __restrict__ Yall, float qscale) {
  __shared__ __align__(16) ushort As[2][128][32];
  __shared__ __align__(16) ushort Bs[2][128][32];

  const int tid = threadIdx.x;
  const int w = tid >> 6, lane = tid & 63;
  const int llo = lane & 15, lhi = lane >> 4;
  const int wm = w >> 1, wn = w & 1;

  const int bid = blockIdx.x;
  const int x = bid & 7, rest = bid >> 3;
  const int ni = rest & 3;
  const int gg = (rest >> 2) * 8 + x;  // 0..191
  const int sec = gg >> 6;             // 0=Q,1=K,2=V
  const int mt = gg & 63;
  const int m0 = mt << 7;
  const int n0s = ni << 7;

  const float* A = (sec == 0) ? Qx : (sec == 1) ? Kx : Vx;
  const float* bias = (sec == 0) ? bq : (sec == 1) ? bk : bv;
  const float scale = (sec == 0) ? qscale : 1.0f;
  const ushort* Wt = Wall + (size_t)(sec * 512 + n0s) * DD;

  const int srow = tid >> 1, scol = (tid & 1) << 4;
  const float* Ag = A + (size_t)(m0 + srow) * DD + scol;
  const ushort* Bg = Wt + (size_t)srow * DD + scol;

  f32x4 acc[4][4];
#pragma unroll
  for (int mi = 0; mi < 4; ++mi)
#pragma unroll
    for (int nj = 0; nj < 4; ++nj) acc[mi][nj] = (f32x4){0.f, 0.f, 0.f, 0.f};

  {
    float4 f0 = *(const float4*)(Ag + 0);
    float4 f1 = *(const float4*)(Ag + 4);
    float4 f2 = *(const float4*)(Ag + 8);
    float4 f3 = *(const float4*)(Ag + 12);
    bf16x8 w0 = *(const bf16x8*)(Bg + 0);
    bf16x8 w1 = *(const bf16x8*)(Bg + 8);
    *(bf16x8*)&As[0][srow][scol] = cvt8(f0, f1);
    *(bf16x8*)&As[0][srow][scol + 8] = cvt8(f2, f3);
    *(bf16x8*)&Bs[0][srow][scol] = w0;
    *(bf16x8*)&Bs[0][srow][scol + 8] = w1;
  }
  __syncthreads();

  int cur = 0;
  for (int t = 0; t < 16; ++t) {
    float4 f0, f1, f2, f3;
    bf16x8 w0, w1;
    if (t < 15) {
      const float* ag = Ag + (t + 1) * 32;
      const ushort* bg = Bg + (t + 1) * 32;
      f0 = *(const float4*)(ag + 0);
      f1 = *(const float4*)(ag + 4);
      f2 = *(const float4*)(ag + 8);
      f3 = *(const float4*)(ag + 12);
      w0 = *(const bf16x8*)(bg + 0);
      w1 = *(const bf16x8*)(bg + 8);
    }
    bf16x8 af[4], bfr[4];
#pragma unroll
    for (int mi = 0; mi < 4; ++mi)
      af[mi] = *(const bf16x8*)&As[cur][wm * 64 + mi * 16 + llo][lhi * 8];
#pragma unroll
    for (int nj = 0; nj < 4; ++nj)
      bfr[nj] = *(const bf16x8*)&Bs[cur][wn * 64 + nj * 16 + llo][lhi * 8];
    __builtin_amdgcn_s_setprio(1);
#pragma unroll
    for (int mi = 0; mi < 4; ++mi)
#pragma unroll
      for (int nj = 0; nj < 4; ++nj)
        acc[mi][nj] = __builtin_amdgcn_mfma_f32_16x16x32_bf16(
            af[mi], bfr[nj], acc[mi][nj], 0, 0, 0);
    __builtin_amdgcn_s_setprio(0);
    if (t < 15) {
      *(bf16x8*)&As[cur ^ 1][srow][scol] = cvt8(f0, f1);
      *(bf16x8*)&As[cur ^ 1][srow][scol + 8] = cvt8(f2, f3);
      *(bf16x8*)&Bs[cur ^ 1][srow][scol] = w0;
      *(bf16x8*)&Bs[cur ^ 1][srow][scol + 8] = w1;
    }
    __syncthreads();
    cur ^= 1;
  }

  float bb[4];
#pragma unroll
  for (int nj = 0; nj < 4; ++nj)
    bb[nj] = bias[n0s + wn * 64 + nj * 16 + llo];

  ushort* Yq = Yall;
  ushort* Yk = Yall + ((size_t)4 << 20);
  ushort* Yv = Yall + ((size_t)8 << 20);
#pragma unroll
  for (int mi = 0; mi < 4; ++mi)
#pragma unroll
    for (int nj = 0; nj < 4; ++nj) {
      int colS = n0s + wn * 64 + nj * 16 + llo;
      int h = colS >> 6, dh = colS & (DH - 1);
#pragma unroll
      for (int r = 0; r < 4; ++r) {
        int row = m0 + wm * 64 + mi * 16 + lhi * 4 + r;
        int bidx = row >> 11, t = row & (TB - 1);
        int bh = bidx * NH + h;
        ushort u = f2bf((acc[mi][nj][r] + bb[nj]) * scale);
        if (sec == 0) {
          Yq[((size_t)(bh * 128 + (t >> 4)) * 2 + (dh >> 5)) * 512 +
             ((((dh >> 3) & 3) << 4) + (t & 15)) * 8 + (dh & 7)] = u;
        } else if (sec == 1) {
          Yk[((size_t)(bh * 32 + (t >> 6)) << 12) +
             (((dh >> 5) << 2) + ((t >> 4) & 3)) * 512 +
             ((((dh >> 3) & 3) << 4) + (t & 15)) * 8 + (dh & 7)] = u;
        } else {
          Yv[((size_t)(bh * 32 + (t >> 6)) << 12) +
             ((((t >> 5) & 1) << 2) + (dh >> 4)) * 512 +
             ((((t >> 3) & 3) << 4) + (dh & 15)) * 8 + (t & 7)] = u;
        }
      }
    }
}

// ---------------------------------------------------------------------------
// O-projection, 4-wave 128x64-tile LDS GEMM (verified R11).
__global__ __launch_bounds__(256) void projo_kernel(
    const ushort* __restrict__ A, const ushort* __restrict__ Wt,
    const float* __restrict__ bias, float* __restrict__ Y) {
  __shared__ __align__(16) ushort As[2][128][32];
  __shared__ __align__(16) ushort Bs[2][64][32];

  const int tid = threadIdx.x;
  const int w = tid >> 6, lane = tid & 63;
  const int llo = lane & 15, lhi = lane >> 4;
  const int wm = w >> 1, wn = w & 1;

  const int bid = blockIdx.x;
  const int x = bid & 7, rest = bid >> 3;
  const int ni = rest & 7;
  const int mt = (rest >> 3) * 8 + x;  // 0..63
  const int m0 = mt << 7;
  const int n0 = ni << 6;
  const int K = 1536;

  const int arow = tid >> 1, acol = (tid & 1) << 4;
  const int brow = tid >> 2, bcol = (tid & 3) << 3;
  const ushort* Ag = A + (size_t)(m0 + arow) * K + acol;
  const ushort* Bg = Wt + (size_t)(n0 + brow) * K + bcol;

  f32x4 acc[4][2];
#pragma unroll
  for (int mi = 0; mi < 4; ++mi)
#pragma unroll
    for (int nj = 0; nj < 2; ++nj) acc[mi][nj] = (f32x4){0.f, 0.f, 0.f, 0.f};

  {
    bf16x8 a0 = *(const bf16x8*)(Ag + 0);
    bf16x8 a1 = *(const bf16x8*)(Ag + 8);
    bf16x8 b0 = *(const bf16x8*)(Bg + 0);
    *(bf16x8*)&As[0][arow][acol] = a0;
    *(bf16x8*)&As[0][arow][acol + 8] = a1;
    *(bf16x8*)&Bs[0][brow][bcol] = b0;
  }
  __syncthreads();

  int cur = 0;
#pragma unroll 2
  for (int t = 0; t < 48; ++t) {
    bf16x8 a0, a1, b0;
    if (t < 47) {
      const ushort* ag = Ag + (t + 1) * 32;
      const ushort* bg = Bg + (t + 1) * 32;
      a0 = *(const bf16x8*)(ag + 0);
      a1 = *(const bf16x8*)(ag + 8);
      b0 = *(const bf16x8*)(bg + 0);
    }
    bf16x8 af[4], bfr[2];
#pragma unroll
    for (int mi = 0; mi < 4; ++mi)
      af[mi] = *(const bf16x8*)&As[cur][wm * 64 + mi * 16 + llo][lhi * 8];
#pragma unroll
    for (int nj = 0; nj < 2; ++nj)
      bfr[nj] = *(const bf16x8*)&Bs[cur][wn * 32 + nj * 16 + llo][lhi * 8];
    __builtin_amdgcn_s_setprio(1);
#pragma unroll
    for (int mi = 0; mi < 4; ++mi)
#pragma unroll
      for (int nj = 0; nj < 2; ++nj)
        acc[mi][nj] = __builtin_amdgcn_mfma_f32_16x16x32_bf16(
            af[mi], bfr[nj], acc[mi][nj], 0, 0, 0);
    __builtin_amdgcn_s_setprio(0);
    if (t < 47) {
      *(bf16x8*)&As[cur ^ 1][arow][acol] = a0;
      *(bf16x8*)&As[cur ^ 1][arow][acol + 8] = a1;
      *(bf16x8*)&Bs[cur ^ 1][brow][bcol] = b0;
    }
    __syncthreads();
    cur ^= 1;
  }

  float bb[2];
#pragma unroll
  for (int nj = 0; nj < 2; ++nj)
    bb[nj] = bias[n0 + wn * 32 + nj * 16 + llo];
#pragma unroll
  for (int mi = 0; mi < 4; ++mi)
#pragma unroll
    for (int nj = 0; nj < 2; ++nj) {
      int col = n0 + wn * 32 + nj * 16 + llo;
#pragma unroll
      for (int r = 0; r < 4; ++r) {
        int row = m0 + wm * 64 + mi * 16 + lhi * 4 + r;
        Y[(size_t)row * DD + col] = acc[mi][nj][r] + bb[nj];
      }
    }
}

// ---------------------------------------------------------------------------
// Swapped-QK^T bf16 MFMA flash attention, fragment-linear operands.
// R12: + cross-tile K prefetch (in-place reload after QK^T);
//      + deferred reductions: lane-local trigger (__any over all lanes ==
//        row-max test exactly), per-lane partial l reduced in epilogue.
//      Common path: ZERO cross-lane shuffles per tile.
__global__ __launch_bounds__(256) void attn_mfma_kernel(
    const ushort* __restrict__ Qf,    // frag-linear, scaled 0.125*log2e
    const ushort* __restrict__ Kf,    // frag-linear
    const ushort* __restrict__ Vf,    // frag-linear (V^T frags)
    const float* __restrict__ mbias,  // [B][T] 0 / -inf
    ushort* __restrict__ Ap) {        // A' [8192][1536]
  __shared__ __align__(16) ushort Plds[4][16][72];

  const int tid = threadIdx.x;
  const int w = tid >> 6, lane = tid & 63;
  const int lhi = lane >> 4, llo = lane & 15;
  const int lane8 = lane * 8;

  const int bid = blockIdx.x;
  const int j = bid >> 3;
  const int bh = (bid & 7) + ((j >> 5) << 3);  // same-bh blocks -> same XCD
  const int qt = j & 31;
  const int b = bh >> 3, h = bh & 7;
  const int q0 = qt << 6;

  const float* mb = mbias + b * TB;
  ushort* pl = &Plds[w][0][0];  // [16][72]

  const ushort* Qb = Qf + ((size_t)((bh << 7) + (q0 >> 4) + w) * 2) * 512 + lane8;
  bf16x8 qa0 = *(const bf16x8*)Qb;
  bf16x8 qa1 = *(const bf16x8*)(Qb + 512);

  const size_t bhK = (size_t)bh << 5;
  f32x4 oacc[4];  // oacc[nt][r]: q-row lhi*4+r, dh = nt*16+llo
#pragma unroll
  for (int nt = 0; nt < 4; ++nt) oacc[nt] = (f32x4){0.f, 0.f, 0.f, 0.f};
  // stats for q-row llo: m row-uniform; l PER-LANE PARTIAL (reduced at end)
  float m = -INFINITY, l = 0.f;

  // K prologue: tile 0 fragments
  bf16x8 kf[8];
  {
    const ushort* Kt0 = Kf + (bhK << 12) + lane8;
#pragma unroll
    for (int i = 0; i < 8; ++i) kf[i] = *(const bf16x8*)(Kt0 + i * 512);
  }

  for (int kt64 = 0; kt64 < 32; ++kt64) {
    // V + mask for THIS tile (consumed at PV / mask-add; latency covered)
    const ushort* Vt = Vf + ((bhK + kt64) << 12) + lane8;
    bf16x8 vf[8];
#pragma unroll
    for (int i = 0; i < 8; ++i) vf[i] = *(const bf16x8*)(Vt + i * 512);
    float4 mb4[4];
#pragma unroll
    for (int nt = 0; nt < 4; ++nt)
      mb4[nt] = *(const float4*)&mb[kt64 * 64 + nt * 16 + lhi * 4];

    // S^T = K Q^T (kf ready from prefetch)
    f32x4 s[4];
    __builtin_amdgcn_s_setprio(1);
#pragma unroll
    for (int nt = 0; nt < 4; ++nt) {
      s[nt] = (f32x4){0.f, 0.f, 0.f, 0.f};
      s[nt] = __builtin_amdgcn_mfma_f32_16x16x32_bf16(kf[nt], qa0, s[nt], 0, 0, 0);
      s[nt] = __builtin_amdgcn_mfma_f32_16x16x32_bf16(kf[4 + nt], qa1, s[nt], 0, 0, 0);
    }
    __builtin_amdgcn_s_setprio(0);

    // prefetch K for next tile (wraps at end; harmless valid loads)
    {
      const ushort* Ktn = Kf + ((bhK + ((kt64 + 1) & 31)) << 12) + lane8;
#pragma unroll
      for (int i = 0; i < 8; ++i) kf[i] = *(const bf16x8*)(Ktn + i * 512);
    }

    // mask bias add (key = nt*16 + lhi*4 + r)
#pragma unroll
    for (int nt = 0; nt < 4; ++nt) {
      s[nt][0] += mb4[nt].x;
      s[nt][1] += mb4[nt].y;
      s[nt][2] += mb4[nt].z;
      s[nt][3] += mb4[nt].w;
    }

    // lane-local max over this lane's 16 keys
    float mx[4];
#pragma unroll
    for (int nt = 0; nt < 4; ++nt)
      mx[nt] = fmaxf(fmaxf(s[nt][0], s[nt][1]), fmaxf(s[nt][2], s[nt][3]));
    float lmax = fmaxf(fmaxf(mx[0], mx[1]), fmaxf(mx[2], mx[3]));

    // deferred-max trigger: __any over all 64 lanes covers every lhi group
    // of every row, so this is EXACTLY the row-max > m+8 test.
    if (__any(lmax > m + 8.f)) {
      float rmax = fmaxf(lmax, __shfl_xor(lmax, 16));
      rmax = fmaxf(rmax, __shfl_xor(rmax, 32));
      float newm = fmaxf(m, rmax);
      float alpha = (newm == -INFINITY) ? 0.f : fast_exp2(m - newm);
      float al[4];
#pragma unroll
      for (int r = 0; r < 4; ++r) al[r] = __shfl(alpha, lhi * 4 + r);
#pragma unroll
      for (int nt = 0; nt < 4; ++nt) {
        oacc[nt][0] *= al[0];
        oacc[nt][1] *= al[1];
        oacc[nt][2] *= al[2];
        oacc[nt][3] *= al[3];
      }
      l *= alpha;
      m = newm;
    }

    // p = exp2(s - m)
#pragma unroll
    for (int nt = 0; nt < 4; ++nt)
#pragma unroll
      for (int r = 0; r < 4; ++r) s[nt][r] = fast_exp2(s[nt][r] - m);
    if (__any(m == -INFINITY)) {  // dead rows (all keys masked): scrub nan
      if (m == -INFINITY) {
#pragma unroll
        for (int nt = 0; nt < 4; ++nt) s[nt] = (f32x4){0.f, 0.f, 0.f, 0.f};
      }
    }
    // per-lane partial l (cross-lane reduce deferred to epilogue)
    float sm[4];
#pragma unroll
    for (int nt = 0; nt < 4; ++nt)
      sm[nt] = (s[nt][0] + s[nt][1]) + (s[nt][2] + s[nt][3]);
    l += (sm[0] + sm[1]) + (sm[2] + sm[3]);

    // P pack -> per-wave LDS (A-layout source form)
#pragma unroll
    for (int nt = 0; nt < 4; ++nt) {
      unsigned int lo = pack2(s[nt][0], s[nt][1]);
      unsigned int hi = pack2(s[nt][2], s[nt][3]);
      *(uint2*)&pl[llo * 72 + nt * 16 + lhi * 4] = make_uint2(lo, hi);
    }

    // O += P V
    __builtin_amdgcn_s_setprio(1);
#pragma unroll
    for (int kc = 0; kc < 2; ++kc) {
      bf16x8 pa = *(const bf16x8*)&pl[llo * 72 + kc * 32 + lhi * 8];
#pragma unroll
      for (int nt = 0; nt < 4; ++nt)
        oacc[nt] = __builtin_amdgcn_mfma_f32_16x16x32_bf16(pa, vf[kc * 4 + nt], oacc[nt], 0, 0, 0);
    }
    __builtin_amdgcn_s_setprio(0);
  }

  // epilogue: reduce per-lane l across the row's 4 lhi lanes, then write
  l += __shfl_xor(l, 16);
  l += __shfl_xor(l, 32);
  float linv = (l > 0.f) ? 1.f / l : 0.f;
  float il[4];
#pragma unroll
  for (int r = 0; r < 4; ++r) il[r] = __shfl(linv, lhi * 4 + r);
  const int t0 = q0 + w * 16 + lhi * 4;
#pragma unroll
  for (int r = 0; r < 4; ++r) {
    size_t rowb = (size_t)(b * TB + t0 + r) * 1536;
#pragma unroll
    for (int nt = 0; nt < 4; ++nt) {
      float o = oacc[nt][r] * il[r];
      ushort hi = f2bf(o);
      ushort lo = f2bf(o - bf2f(hi));
      int c = h * DH + nt * 16 + llo;
      Ap[rowb + c] = hi;
      Ap[rowb + 512 + c] = lo;
      Ap[rowb + 1024 + c] = hi;
    }
  }
}

// ---------------------------------------------------------------------------
extern "C" void kernel_launch(void* const* d_in, const int* in_sizes, int n_in,
                              void* d_out, int out_size, void* d_ws,
                              size_t ws_size, hipStream_t stream) {
  (void)in_sizes; (void)n_in; (void)out_size; (void)ws_size;
  const float* q = (const float*)d_in[0];
  const float* k = (const float*)d_in[1];
  const float* v = (const float*)d_in[2];
  const void* pm = d_in[3];
  const float* Wq = (const float*)d_in[4];
  const float* bq = (const float*)d_in[5];
  const float* Wk = (const float*)d_in[6];
  const float* bk = (const float*)d_in[7];
  const float* Wv = (const float*)d_in[8];
  const float* bv = (const float*)d_in[9];
  const float* Wo = (const float*)d_in[10];
  const float* bo = (const float*)d_in[11];

  char* ws = (char*)d_ws;
  const size_t MB = (size_t)1 << 20;
  // [0,24MB): A' (attention output, split-bf16 rows)
  ushort* Ap = (ushort*)(ws);
  // [24,25.5MB): Wall = [Wq^T | Wk^T | Wv^T] bf16
  ushort* Wall = (ushort*)(ws + 24 * MB);
  // [26,27.5MB): split O-weight
  ushort* Wot = (ushort*)(ws + 26 * MB);
  // [32,56MB): fragment-linear Q/K/V (8MB sections)
  ushort* Qh = (ushort*)(ws + 32 * MB);
  float* mbias = (float*)(ws + 56 * MB);
  int* mode = (int*)(ws + 56 * MB + 40960);

  mask_detect_kernel<<<1, 256, 0, stream>>>((const unsigned char*)pm, mode);
  mask_build_kernel<<<32, 256, 0, stream>>>(pm, mode, mbias);

  wtrans3_kernel<<<dim3(8, 8, 3), 256, 0, stream>>>(Wq, Wk, Wv, Wall);
  wtrans_split_kernel<<<dim3(8, 8), 256, 0, stream>>>(Wo, Wot);

  // Q scale folds 1/sqrt(64) * log2(e) for the exp2-domain softmax
  const float qscale = 0.125f * 1.4426950408889634f;
  projqkv_kernel<<<768, 256, 0, stream>>>(q, k, v, Wall,
                                          bq, bk, bv, Qh, qscale);

  attn_mfma_kernel<<<1024, 256, 0, stream>>>(
      Qh, Qh + ((size_t)4 << 20), Qh + ((size_t)8 << 20), mbias, Ap);

  projo_kernel<<<512, 256, 0, stream>>>(Ap, Wot, bo, (float*)d_out);
}